// Round 2
// baseline (701.124 us; speedup 1.0000x reference)
//
#include <hip/hip_runtime.h>
#include <hip/hip_bf16.h>
#include <math.h>

#define B_GRAPHS 64
#define N_NODES  2048
#define E_DIM    16
#define M_TOT    (B_GRAPHS * N_NODES)   // 131072
#define K_COND   64
#define MLP_IN   192
#define HID      512
#define POOLD    128
#define BN_EPS   1e-5f

// GEMM tiling
#define BM 128
#define BN 128
#define BK 32
#define LDP 40   // padded LDS row length in shorts (80B = 5*16B, keeps b128 alignment)

typedef __attribute__((ext_vector_type(8))) short bfrag8;
typedef __attribute__((ext_vector_type(4))) float facc4;

__device__ __forceinline__ unsigned short f2b(float f) {
    unsigned int x = __builtin_bit_cast(unsigned int, f);
    unsigned int r = x + 0x7fffu + ((x >> 16) & 1u);
    return (unsigned short)(r >> 16);
}
__device__ __forceinline__ float b2f(unsigned short u) {
    unsigned int x = ((unsigned int)u) << 16;
    return __builtin_bit_cast(float, x);
}
__device__ __forceinline__ float gelu_exact(float y) {
    return 0.5f * y * (1.0f + erff(y * 0.70710678118654752440f));
}

// ---------------- pool: x [131072,16] -> pooled [64,128] ----------------
__global__ void pool_kernel(const float* __restrict__ x, float* __restrict__ pooled) {
    int g = blockIdx.x;           // 64 blocks
    int t = threadIdx.x;          // 128 threads
    int h = t >> 2, w = t & 3;
    const float* base = x + (size_t)g * N_NODES * E_DIM + (size_t)h * 64 * E_DIM + w * 4;
    float s = 0.f;
    #pragma unroll 4
    for (int r = 0; r < 64; ++r) {
        float4 v = *reinterpret_cast<const float4*>(base + (size_t)r * E_DIM);
        s += v.x + v.y + v.z + v.w;
    }
    pooled[g * POOLD + h * 4 + w] = s * (1.0f / 256.0f);
}

// ------------- gbias[g][n] = pooled[g] . W1[n,64:192] + b1[n] -------------
__global__ void gbias_kernel(const float* __restrict__ pooled, const float* __restrict__ W1,
                             const float* __restrict__ b1, float* __restrict__ gbias) {
    int g = blockIdx.x;   // 64
    int n = threadIdx.x;  // 512
    const float* pr = pooled + g * POOLD;
    const float* wr = W1 + (size_t)n * MLP_IN + K_COND;
    float s = b1[n];
    #pragma unroll 4
    for (int k = 0; k < POOLD; ++k) s += pr[k] * wr[k];
    gbias[g * HID + n] = s;
}

// ------------- GEMM1: H1[m][n] = cond[m][0:64] @ W1[n][0:64]^T + gbias[batch[m]][n] -------------
__global__ __launch_bounds__(256) void gemm1_kernel(const float* __restrict__ A,
                                                    const float* __restrict__ W,
                                                    const int* __restrict__ batch,
                                                    const float* __restrict__ gbias,
                                                    unsigned short* __restrict__ H1) {
    __shared__ unsigned short As[BM * LDP];
    __shared__ unsigned short Bs[BN * LDP];
    const int t = threadIdx.x;
    const int r0 = blockIdx.x * BM, c0 = blockIdx.y * BN;
    const int l = t & 63, wid = t >> 6;
    const int wr = wid >> 1, wc = wid & 1;
    const int ln = l & 15, kg = l >> 4;
    const int srow = t >> 1;
    const int koff = (t & 1) * 16;

    facc4 acc[4][4];
    const facc4 z = {0.f, 0.f, 0.f, 0.f};
    #pragma unroll
    for (int a = 0; a < 4; ++a)
        #pragma unroll
        for (int b = 0; b < 4; ++b) acc[a][b] = z;

    for (int kk = 0; kk < K_COND; kk += BK) {
        // stage A (cond fp32 -> bf16)
        {
            const float* src = A + (size_t)(r0 + srow) * K_COND + kk + koff;
            unsigned short tmp[16];
            #pragma unroll
            for (int i = 0; i < 16; i += 4) {
                float4 v = *reinterpret_cast<const float4*>(src + i);
                tmp[i + 0] = f2b(v.x); tmp[i + 1] = f2b(v.y);
                tmp[i + 2] = f2b(v.z); tmp[i + 3] = f2b(v.w);
            }
            bfrag8* dst = reinterpret_cast<bfrag8*>(&As[srow * LDP + koff]);
            dst[0] = *reinterpret_cast<bfrag8*>(&tmp[0]);
            dst[1] = *reinterpret_cast<bfrag8*>(&tmp[8]);
        }
        // stage B (W1 rows c0+srow, cols kk+koff, stride MLP_IN)
        {
            const float* src = W + (size_t)(c0 + srow) * MLP_IN + kk + koff;
            unsigned short tmp[16];
            #pragma unroll
            for (int i = 0; i < 16; i += 4) {
                float4 v = *reinterpret_cast<const float4*>(src + i);
                tmp[i + 0] = f2b(v.x); tmp[i + 1] = f2b(v.y);
                tmp[i + 2] = f2b(v.z); tmp[i + 3] = f2b(v.w);
            }
            bfrag8* dst = reinterpret_cast<bfrag8*>(&Bs[srow * LDP + koff]);
            dst[0] = *reinterpret_cast<bfrag8*>(&tmp[0]);
            dst[1] = *reinterpret_cast<bfrag8*>(&tmp[8]);
        }
        __syncthreads();
        bfrag8 af[4], bfv[4];
        #pragma unroll
        for (int a = 0; a < 4; ++a)
            af[a] = *reinterpret_cast<const bfrag8*>(&As[(wr * 64 + a * 16 + ln) * LDP + 8 * kg]);
        #pragma unroll
        for (int b = 0; b < 4; ++b)
            bfv[b] = *reinterpret_cast<const bfrag8*>(&Bs[(wc * 64 + b * 16 + ln) * LDP + 8 * kg]);
        #pragma unroll
        for (int a = 0; a < 4; ++a)
            #pragma unroll
            for (int b = 0; b < 4; ++b)
                acc[a][b] = __builtin_amdgcn_mfma_f32_16x16x32_bf16(af[a], bfv[b], acc[a][b], 0, 0, 0);
        __syncthreads();
    }
    // epilogue: + gbias[batch[row]][col], store bf16
    #pragma unroll
    for (int a = 0; a < 4; ++a) {
        #pragma unroll
        for (int i = 0; i < 4; ++i) {
            int row = r0 + wr * 64 + a * 16 + kg * 4 + i;
            int g = batch[row];
            const float* gb = gbias + (size_t)g * HID;
            #pragma unroll
            for (int b = 0; b < 4; ++b) {
                int col = c0 + wc * 64 + b * 16 + ln;
                float v = acc[a][b][i] + gb[col];
                H1[(size_t)row * HID + col] = f2b(v);
            }
        }
    }
}

// ------------- GEMM2: H2 = act1(H1) @ W2^T + b2  (H1 already activated in-place) -------------
__global__ __launch_bounds__(256) void gemm2_kernel(const unsigned short* __restrict__ A,
                                                    const float* __restrict__ W,
                                                    const float* __restrict__ bias,
                                                    unsigned short* __restrict__ H2) {
    __shared__ unsigned short As[BM * LDP];
    __shared__ unsigned short Bs[BN * LDP];
    const int t = threadIdx.x;
    const int r0 = blockIdx.x * BM, c0 = blockIdx.y * BN;
    const int l = t & 63, wid = t >> 6;
    const int wr = wid >> 1, wc = wid & 1;
    const int ln = l & 15, kg = l >> 4;
    const int srow = t >> 1;
    const int koff = (t & 1) * 16;

    facc4 acc[4][4];
    const facc4 z = {0.f, 0.f, 0.f, 0.f};
    #pragma unroll
    for (int a = 0; a < 4; ++a)
        #pragma unroll
        for (int b = 0; b < 4; ++b) acc[a][b] = z;

    for (int kk = 0; kk < HID; kk += BK) {
        // stage A (bf16 direct)
        {
            const unsigned short* src = A + (size_t)(r0 + srow) * HID + kk + koff;
            bfrag8 v0 = *reinterpret_cast<const bfrag8*>(src);
            bfrag8 v1 = *reinterpret_cast<const bfrag8*>(src + 8);
            bfrag8* dst = reinterpret_cast<bfrag8*>(&As[srow * LDP + koff]);
            dst[0] = v0; dst[1] = v1;
        }
        // stage B (W2 fp32 -> bf16)
        {
            const float* src = W + (size_t)(c0 + srow) * HID + kk + koff;
            unsigned short tmp[16];
            #pragma unroll
            for (int i = 0; i < 16; i += 4) {
                float4 v = *reinterpret_cast<const float4*>(src + i);
                tmp[i + 0] = f2b(v.x); tmp[i + 1] = f2b(v.y);
                tmp[i + 2] = f2b(v.z); tmp[i + 3] = f2b(v.w);
            }
            bfrag8* dst = reinterpret_cast<bfrag8*>(&Bs[srow * LDP + koff]);
            dst[0] = *reinterpret_cast<bfrag8*>(&tmp[0]);
            dst[1] = *reinterpret_cast<bfrag8*>(&tmp[8]);
        }
        __syncthreads();
        bfrag8 af[4], bfv[4];
        #pragma unroll
        for (int a = 0; a < 4; ++a)
            af[a] = *reinterpret_cast<const bfrag8*>(&As[(wr * 64 + a * 16 + ln) * LDP + 8 * kg]);
        #pragma unroll
        for (int b = 0; b < 4; ++b)
            bfv[b] = *reinterpret_cast<const bfrag8*>(&Bs[(wc * 64 + b * 16 + ln) * LDP + 8 * kg]);
        #pragma unroll
        for (int a = 0; a < 4; ++a)
            #pragma unroll
            for (int b = 0; b < 4; ++b)
                acc[a][b] = __builtin_amdgcn_mfma_f32_16x16x32_bf16(af[a], bfv[b], acc[a][b], 0, 0, 0);
        __syncthreads();
    }
    #pragma unroll
    for (int a = 0; a < 4; ++a) {
        #pragma unroll
        for (int i = 0; i < 4; ++i) {
            int row = r0 + wr * 64 + a * 16 + kg * 4 + i;
            #pragma unroll
            for (int b = 0; b < 4; ++b) {
                int col = c0 + wc * 64 + b * 16 + ln;
                float v = acc[a][b][i] + bias[col];
                H2[(size_t)row * HID + col] = f2b(v);
            }
        }
    }
}

// ------------- column stats: sums[0:512]=sum, sums[512:1024]=sumsq (atomic) -------------
__global__ __launch_bounds__(256) void stats_kernel(const unsigned short* __restrict__ H,
                                                    float* __restrict__ sums) {
    __shared__ float ls[HID], lq[HID];
    int t = threadIdx.x;
    for (int i = t; i < HID; i += 256) { ls[i] = 0.f; lq[i] = 0.f; }
    __syncthreads();
    int c = (t & 63) * 8;
    int rbase = blockIdx.x * 128 + (t >> 6);
    float s[8], q[8];
    #pragma unroll
    for (int j = 0; j < 8; ++j) { s[j] = 0.f; q[j] = 0.f; }
    for (int i = 0; i < 32; ++i) {
        const unsigned short* p = H + (size_t)(rbase + i * 4) * HID + c;
        bfrag8 v = *reinterpret_cast<const bfrag8*>(p);
        #pragma unroll
        for (int j = 0; j < 8; ++j) {
            float x = b2f((unsigned short)v[j]);
            s[j] += x; q[j] += x * x;
        }
    }
    #pragma unroll
    for (int j = 0; j < 8; ++j) {
        atomicAdd(&ls[c + j], s[j]);
        atomicAdd(&lq[c + j], q[j]);
    }
    __syncthreads();
    for (int i = t; i < HID; i += 256) {
        atomicAdd(&sums[i], ls[i]);
        atomicAdd(&sums[HID + i], lq[i]);
    }
}

// ------------- finalize: ss[0:512]=scale, ss[512:1024]=shift -------------
__global__ void finalize_kernel(const float* __restrict__ sums, const float* __restrict__ g,
                                const float* __restrict__ be, float* __restrict__ ss) {
    int n = threadIdx.x;  // 512
    float mean = sums[n] * (1.0f / M_TOT);
    float var = sums[HID + n] * (1.0f / M_TOT) - mean * mean;
    float sc = g[n] * rsqrtf(var + BN_EPS);
    ss[n] = sc;
    ss[HID + n] = be[n] - mean * sc;
}

// ------------- act: H = gelu(H*scale+shift) in place (bf16) -------------
__global__ __launch_bounds__(256) void act_kernel(unsigned short* __restrict__ H,
                                                  const float* __restrict__ ss) {
    size_t idx = ((size_t)blockIdx.x * 256 + threadIdx.x) * 8;
    int col = (int)(idx & (HID - 1));
    bfrag8 v = *reinterpret_cast<bfrag8*>(&H[idx]);
    #pragma unroll
    for (int j = 0; j < 8; ++j) {
        float x = b2f((unsigned short)v[j]);
        float y = x * ss[col + j] + ss[HID + col + j];
        y = gelu_exact(y);
        v[j] = (short)f2b(y);
    }
    *reinterpret_cast<bfrag8*>(&H[idx]) = v;
}

// ------------- G3: out[m][0:3] = act2(H2[m]) . W3^T + b3 -------------
__global__ __launch_bounds__(256) void g3_kernel(const unsigned short* __restrict__ H2,
                                                 const float* __restrict__ ss2,
                                                 const float* __restrict__ W3,
                                                 const float* __restrict__ b3,
                                                 float* __restrict__ out) {
    int row = blockIdx.x * 256 + threadIdx.x;
    const unsigned short* p = H2 + (size_t)row * HID;
    float o0 = 0.f, o1 = 0.f, o2 = 0.f;
    for (int k = 0; k < HID; k += 8) {
        bfrag8 v = *reinterpret_cast<const bfrag8*>(p + k);
        #pragma unroll
        for (int j = 0; j < 8; ++j) {
            float x = b2f((unsigned short)v[j]);
            float y = x * ss2[k + j] + ss2[HID + k + j];
            y = gelu_exact(y);
            o0 += y * W3[k + j];
            o1 += y * W3[HID + k + j];
            o2 += y * W3[2 * HID + k + j];
        }
    }
    out[(size_t)row * 3 + 0] = o0 + b3[0];
    out[(size_t)row * 3 + 1] = o1 + b3[1];
    out[(size_t)row * 3 + 2] = o2 + b3[2];
}

extern "C" void kernel_launch(void* const* d_in, const int* in_sizes, int n_in,
                              void* d_out, int out_size, void* d_ws, size_t ws_size,
                              hipStream_t stream) {
    const float* x     = (const float*)d_in[0];
    const int*   batch = (const int*)d_in[1];
    const float* cond  = (const float*)d_in[2];
    const float* W1    = (const float*)d_in[3];
    const float* b1    = (const float*)d_in[4];
    const float* g1    = (const float*)d_in[5];
    const float* be1   = (const float*)d_in[6];
    const float* W2    = (const float*)d_in[7];
    const float* b2    = (const float*)d_in[8];
    const float* g2    = (const float*)d_in[9];
    const float* be2   = (const float*)d_in[10];
    const float* W3    = (const float*)d_in[11];
    const float* b3    = (const float*)d_in[12];

    const size_t H_BYTES = (size_t)M_TOT * HID * 2;  // 134,217,728
    // d_ws holds ONLY the two H buffers: exactly 256 MiB total.
    if (ws_size < 2 * H_BYTES) return;  // clean absmax fail instead of OOB crash
    char* ws = (char*)d_ws;
    unsigned short* H1 = (unsigned short*)ws;
    unsigned short* H2 = (unsigned short*)(ws + H_BYTES);

    // Small scratch lives in d_out (1.5 MB of floats) until g3 overwrites it.
    float* outf   = (float*)d_out;
    float* pooled = outf;                       // 8192 floats
    float* gbias  = pooled + B_GRAPHS * POOLD;  // 32768 floats
    float* sums1  = gbias + B_GRAPHS * HID;     // 1024
    float* sums2  = sums1 + 2 * HID;            // 1024
    float* ss1    = sums2 + 2 * HID;            // 1024   (total 44032 < 393216 floats)
    // ss2 goes into the H1 region, which is dead once gemm2 has run.
    float* ss2    = (float*)ws;

    hipMemsetAsync(sums1, 0, 2 * 2 * HID * sizeof(float), stream);

    pool_kernel<<<B_GRAPHS, 128, 0, stream>>>(x, pooled);
    gbias_kernel<<<B_GRAPHS, HID, 0, stream>>>(pooled, W1, b1, gbias);
    gemm1_kernel<<<dim3(M_TOT / BM, HID / BN), 256, 0, stream>>>(cond, W1, batch, gbias, H1);
    stats_kernel<<<M_TOT / 128, 256, 0, stream>>>(H1, sums1);
    finalize_kernel<<<1, HID, 0, stream>>>(sums1, g1, be1, ss1);
    act_kernel<<<(M_TOT * HID / 8) / 256, 256, 0, stream>>>(H1, ss1);
    gemm2_kernel<<<dim3(M_TOT / BM, HID / BN), 256, 0, stream>>>(H1, W2, b2, H2);
    stats_kernel<<<M_TOT / 128, 256, 0, stream>>>(H2, sums2);
    finalize_kernel<<<1, HID, 0, stream>>>(sums2, g2, be2, ss2);
    g3_kernel<<<M_TOT / 256, 256, 0, stream>>>(H2, ss2, W3, b3, outf);
}

// Round 3
// 386.441 us; speedup vs baseline: 1.8143x; 1.8143x over previous
//
#include <hip/hip_runtime.h>
#include <hip/hip_bf16.h>
#include <math.h>
#include <stdint.h>

#define B_GRAPHS 64
#define N_NODES  2048
#define E_DIM    16
#define M_TOT    (B_GRAPHS * N_NODES)   // 131072
#define K_COND   64
#define MLP_IN   192
#define HID      512
#define POOLD    128
#define BN_EPS   1e-5f

typedef __attribute__((ext_vector_type(8))) short bfrag8;
typedef __attribute__((ext_vector_type(4))) float facc4;

__device__ __forceinline__ unsigned short f2b(float f) {
    unsigned int x = __builtin_bit_cast(unsigned int, f);
    unsigned int r = x + 0x7fffu + ((x >> 16) & 1u);
    return (unsigned short)(r >> 16);
}
__device__ __forceinline__ float b2f(unsigned short u) {
    unsigned int x = ((unsigned int)u) << 16;
    return __builtin_bit_cast(float, x);
}

// Branch-free GELU: erf via Abramowitz-Stegun 7.1.26 (|err| <= 1.5e-7),
// one v_rcp + one v_exp + 5 FMA. No divergent paths, no libcall.
__device__ __forceinline__ float gelu_fast(float y) {
    float x  = y * 0.70710678118654752440f;
    float ax = fabsf(x);
    float t  = __builtin_amdgcn_rcpf(fmaf(0.3275911f, ax, 1.0f));
    float p  = fmaf(1.061405429f, t, -1.453152027f);
    p = fmaf(p, t, 1.421413741f);
    p = fmaf(p, t, -0.284496736f);
    p = fmaf(p, t, 0.254829592f);
    p = p * t;
    float e = __expf(-x * x);
    float erfax = fmaf(-p, e, 1.0f);          // erf(|x|)
    float erfx  = copysignf(erfax, x);
    return 0.5f * y * (1.0f + erfx);
}

#define GLOAD_LDS16(g, l)                                                        \
    __builtin_amdgcn_global_load_lds(                                            \
        (const __attribute__((address_space(1))) unsigned int*)(const void*)(g), \
        (__attribute__((address_space(3))) unsigned int*)(void*)(l), 16, 0, 0)

// ---------------- pool: x [131072,16] -> pooled [64,128] ----------------
__global__ void pool_kernel(const float* __restrict__ x, float* __restrict__ pooled) {
    int g = blockIdx.x;           // 64 blocks
    int t = threadIdx.x;          // 128 threads
    int h = t >> 2, w = t & 3;
    const float* base = x + (size_t)g * N_NODES * E_DIM + (size_t)h * 64 * E_DIM + w * 4;
    float s = 0.f;
    #pragma unroll 4
    for (int r = 0; r < 64; ++r) {
        float4 v = *reinterpret_cast<const float4*>(base + (size_t)r * E_DIM);
        s += v.x + v.y + v.z + v.w;
    }
    pooled[g * POOLD + h * 4 + w] = s * (1.0f / 256.0f);
}

// ------------- gbias[g][n] = pooled[g] . W1[n,64:192] + b1[n] -------------
__global__ void gbias_kernel(const float* __restrict__ pooled, const float* __restrict__ W1,
                             const float* __restrict__ b1, float* __restrict__ gbias) {
    int g = blockIdx.x;   // 64
    int n = threadIdx.x;  // 512
    const float* pr = pooled + g * POOLD;
    const float* wr = W1 + (size_t)n * MLP_IN + K_COND;
    float s = b1[n];
    #pragma unroll 4
    for (int k = 0; k < POOLD; ++k) s = fmaf(pr[k], wr[k], s);
    gbias[g * HID + n] = s;
}

// ------------- contiguous fp32 -> bf16 -------------
__global__ __launch_bounds__(256) void cvt_kernel(const float* __restrict__ s,
                                                  unsigned short* __restrict__ d) {
    size_t i = ((size_t)blockIdx.x * 256 + threadIdx.x) * 8;
    float4 v0 = *reinterpret_cast<const float4*>(s + i);
    float4 v1 = *reinterpret_cast<const float4*>(s + i + 4);
    unsigned short t[8] = {f2b(v0.x), f2b(v0.y), f2b(v0.z), f2b(v0.w),
                           f2b(v1.x), f2b(v1.y), f2b(v1.z), f2b(v1.w)};
    *reinterpret_cast<bfrag8*>(d + i) = *reinterpret_cast<bfrag8*>(t);
}

// ------------- W1[:, 0:64] strided fp32 -> bf16 [512,64] -------------
__global__ __launch_bounds__(256) void w1a_cvt_kernel(const float* __restrict__ W1,
                                                      unsigned short* __restrict__ d) {
    int i = (blockIdx.x * 256 + threadIdx.x) * 8;   // 0..32768
    int n = i >> 6, k = i & 63;
    const float* s = W1 + (size_t)n * MLP_IN + k;
    float4 v0 = *reinterpret_cast<const float4*>(s);
    float4 v1 = *reinterpret_cast<const float4*>(s + 4);
    unsigned short t[8] = {f2b(v0.x), f2b(v0.y), f2b(v0.z), f2b(v0.w),
                           f2b(v1.x), f2b(v1.y), f2b(v1.z), f2b(v1.w)};
    *reinterpret_cast<bfrag8*>(d + i) = *reinterpret_cast<bfrag8*>(t);
}

// ------------- m97-style bf16 GEMM: C[M,512] = A[M,KDIM] @ B[512,KDIM]^T -------------
// 128x128 tile, BK=32, 4 waves, global_load_lds width 16, linear LDS [128][32].
template <int KDIM, bool GBIAS>
__global__ __launch_bounds__(256) void gemm_lds_kernel(const unsigned short* __restrict__ A,
                                                       const unsigned short* __restrict__ Bm,
                                                       const int* __restrict__ batch,
                                                       const float* __restrict__ addv,
                                                       unsigned short* __restrict__ C) {
    __shared__ unsigned short As[128 * 32];
    __shared__ unsigned short Bs[128 * 32];
    const int t  = threadIdx.x;
    const int r0 = blockIdx.x * 128, c0 = blockIdx.y * 128;
    const int l  = t & 63, w = t >> 6;
    const int wr = w >> 1, wc = w & 1;
    const int ln = l & 15, kg = l >> 4;
    const int lrow = l >> 2, lslot = l & 3;   // staging: lane -> (row-in-chunk, 16B slot)

    facc4 acc[4][4];
    const facc4 z = {0.f, 0.f, 0.f, 0.f};
    #pragma unroll
    for (int a = 0; a < 4; ++a)
        #pragma unroll
        for (int b = 0; b < 4; ++b) acc[a][b] = z;

    for (int kk = 0; kk < KDIM; kk += 32) {
        #pragma unroll
        for (int c = 0; c < 2; ++c) {
            const int chunk = w * 2 + c;            // 16 rows per 1KB chunk
            const unsigned short* ga =
                A + (size_t)(r0 + chunk * 16 + lrow) * KDIM + kk + lslot * 8;
            GLOAD_LDS16(ga, &As[chunk * 512]);
            const unsigned short* gb =
                Bm + (size_t)(c0 + chunk * 16 + lrow) * KDIM + kk + lslot * 8;
            GLOAD_LDS16(gb, &Bs[chunk * 512]);
        }
        __syncthreads();
        bfrag8 af[4], bf[4];
        #pragma unroll
        for (int a = 0; a < 4; ++a)
            af[a] = *reinterpret_cast<const bfrag8*>(&As[(wr * 64 + a * 16 + ln) * 32 + kg * 8]);
        #pragma unroll
        for (int b = 0; b < 4; ++b)
            bf[b] = *reinterpret_cast<const bfrag8*>(&Bs[(wc * 64 + b * 16 + ln) * 32 + kg * 8]);
        #pragma unroll
        for (int a = 0; a < 4; ++a)
            #pragma unroll
            for (int b = 0; b < 4; ++b)
                acc[a][b] = __builtin_amdgcn_mfma_f32_16x16x32_bf16(af[a], bf[b], acc[a][b], 0, 0, 0);
        __syncthreads();
    }
    #pragma unroll
    for (int a = 0; a < 4; ++a) {
        #pragma unroll
        for (int i = 0; i < 4; ++i) {
            int row = r0 + wr * 64 + a * 16 + kg * 4 + i;
            const float* av = GBIAS ? (addv + (size_t)batch[row] * HID) : addv;
            #pragma unroll
            for (int b = 0; b < 4; ++b) {
                int col = c0 + wc * 64 + b * 16 + ln;
                C[(size_t)row * HID + col] = f2b(acc[a][b][i] + av[col]);
            }
        }
    }
}

// ------------- column stats: sums[0:512]=sum, sums[512:1024]=sumsq (atomic) -------------
__global__ __launch_bounds__(256) void stats_kernel(const unsigned short* __restrict__ H,
                                                    float* __restrict__ sums) {
    __shared__ float ls[HID], lq[HID];
    int t = threadIdx.x;
    for (int i = t; i < HID; i += 256) { ls[i] = 0.f; lq[i] = 0.f; }
    __syncthreads();
    int c = (t & 63) * 8;
    int rbase = blockIdx.x * 128 + (t >> 6);
    float s[8], q[8];
    #pragma unroll
    for (int j = 0; j < 8; ++j) { s[j] = 0.f; q[j] = 0.f; }
    for (int i = 0; i < 32; ++i) {
        const unsigned short* p = H + (size_t)(rbase + i * 4) * HID + c;
        bfrag8 v = *reinterpret_cast<const bfrag8*>(p);
        #pragma unroll
        for (int j = 0; j < 8; ++j) {
            float x = b2f((unsigned short)v[j]);
            s[j] += x; q[j] = fmaf(x, x, q[j]);
        }
    }
    #pragma unroll
    for (int j = 0; j < 8; ++j) {
        atomicAdd(&ls[c + j], s[j]);
        atomicAdd(&lq[c + j], q[j]);
    }
    __syncthreads();
    for (int i = t; i < HID; i += 256) {
        atomicAdd(&sums[i], ls[i]);
        atomicAdd(&sums[HID + i], lq[i]);
    }
}

// ------------- finalize: ss[0:512]=scale, ss[512:1024]=shift -------------
__global__ void finalize_kernel(const float* __restrict__ sums, const float* __restrict__ g,
                                const float* __restrict__ be, float* __restrict__ ss) {
    int n = threadIdx.x;  // 512
    float mean = sums[n] * (1.0f / M_TOT);
    float var = sums[HID + n] * (1.0f / M_TOT) - mean * mean;
    float sc = g[n] * rsqrtf(var + BN_EPS);
    ss[n] = sc;
    ss[HID + n] = be[n] - mean * sc;
}

// ------------- act: H = gelu(H*scale+shift) in place (bf16) -------------
__global__ __launch_bounds__(256) void act_kernel(unsigned short* __restrict__ H,
                                                  const float* __restrict__ ss) {
    size_t idx = ((size_t)blockIdx.x * 256 + threadIdx.x) * 8;
    int col = (int)(idx & (HID - 1));
    bfrag8 v = *reinterpret_cast<bfrag8*>(&H[idx]);
    #pragma unroll
    for (int j = 0; j < 8; ++j) {
        float x = b2f((unsigned short)v[j]);
        float y = fmaf(x, ss[col + j], ss[HID + col + j]);
        y = gelu_fast(y);
        v[j] = (short)f2b(y);
    }
    *reinterpret_cast<bfrag8*>(&H[idx]) = v;
}

// ------------- G3: out[m][0:3] = act2(H2[m]) . W3^T + b3  (8 lanes per row) -------------
__global__ __launch_bounds__(256) void g3_kernel(const unsigned short* __restrict__ H2,
                                                 const float* __restrict__ ss2,
                                                 const float* __restrict__ W3,
                                                 const float* __restrict__ b3,
                                                 float* __restrict__ out) {
    int t = threadIdx.x;
    int l = t & 63, w = t >> 6;
    int rsub = l >> 3, lk = l & 7;
    int row = blockIdx.x * 32 + w * 8 + rsub;
    const unsigned short* p = H2 + (size_t)row * HID;
    float o0 = 0.f, o1 = 0.f, o2 = 0.f;
    #pragma unroll
    for (int it = 0; it < 8; ++it) {
        int k = it * 64 + lk * 8;
        bfrag8 v = *reinterpret_cast<const bfrag8*>(p + k);
        #pragma unroll
        for (int j = 0; j < 8; ++j) {
            float x = b2f((unsigned short)v[j]);
            float y = fmaf(x, ss2[k + j], ss2[HID + k + j]);
            y = gelu_fast(y);
            o0 = fmaf(y, W3[k + j], o0);
            o1 = fmaf(y, W3[HID + k + j], o1);
            o2 = fmaf(y, W3[2 * HID + k + j], o2);
        }
    }
    #pragma unroll
    for (int m = 1; m < 8; m <<= 1) {
        o0 += __shfl_xor(o0, m, 64);
        o1 += __shfl_xor(o1, m, 64);
        o2 += __shfl_xor(o2, m, 64);
    }
    if (lk == 0) {
        out[(size_t)row * 3 + 0] = o0 + b3[0];
        out[(size_t)row * 3 + 1] = o1 + b3[1];
        out[(size_t)row * 3 + 2] = o2 + b3[2];
    }
}

extern "C" void kernel_launch(void* const* d_in, const int* in_sizes, int n_in,
                              void* d_out, int out_size, void* d_ws, size_t ws_size,
                              hipStream_t stream) {
    const float* x     = (const float*)d_in[0];
    const int*   batch = (const int*)d_in[1];
    const float* cond  = (const float*)d_in[2];
    const float* W1    = (const float*)d_in[3];
    const float* b1    = (const float*)d_in[4];
    const float* g1    = (const float*)d_in[5];
    const float* be1   = (const float*)d_in[6];
    const float* W2    = (const float*)d_in[7];
    const float* b2    = (const float*)d_in[8];
    const float* g2    = (const float*)d_in[9];
    const float* be2   = (const float*)d_in[10];
    const float* W3    = (const float*)d_in[11];
    const float* b3    = (const float*)d_in[12];

    const size_t H_BYTES = (size_t)M_TOT * HID * 2;  // 134,217,728
    if (ws_size < 2 * H_BYTES) return;               // clean fail instead of OOB crash
    char* ws = (char*)d_ws;
    unsigned short* H1 = (unsigned short*)ws;
    unsigned short* H2 = (unsigned short*)(ws + H_BYTES);
    // condbf [131072,64] bf16 (16.7MB) shares the H2 region: dead before gemm2 writes H2.
    unsigned short* condbf = (unsigned short*)(ws + H_BYTES);

    // Small scratch lives in d_out (1.5MB of floats) until g3 overwrites it.
    float* outf   = (float*)d_out;
    float* pooled = outf;                        // 8192 floats
    float* gbias  = pooled + B_GRAPHS * POOLD;   // 32768 floats
    float* sums1  = gbias + B_GRAPHS * HID;      // 1024
    float* sums2  = sums1 + 2 * HID;             // 1024
    float* ss1    = sums2 + 2 * HID;             // 1024
    unsigned short* W2bf  = (unsigned short*)(ss1 + HID * 2);        // 262144 shorts (512KB)
    unsigned short* W1abf = W2bf + HID * HID;                        // 32768 shorts (64KB)
    // (total d_out scratch: 44032 floats + 576KB = ~750KB < 1.5MB)
    // ss2 goes into the H1 region, dead once gemm2 has consumed H1.
    float* ss2 = (float*)ws;

    hipMemsetAsync(sums1, 0, 2 * 2 * HID * sizeof(float), stream);

    pool_kernel<<<B_GRAPHS, 128, 0, stream>>>(x, pooled);
    gbias_kernel<<<B_GRAPHS, HID, 0, stream>>>(pooled, W1, b1, gbias);
    cvt_kernel<<<(M_TOT * K_COND / 8) / 256, 256, 0, stream>>>(cond, condbf);
    w1a_cvt_kernel<<<(HID * K_COND / 8) / 256, 256, 0, stream>>>(W1, W1abf);
    cvt_kernel<<<(HID * HID / 8) / 256, 256, 0, stream>>>(W2, W2bf);

    gemm_lds_kernel<K_COND, true><<<dim3(M_TOT / 128, HID / 128), 256, 0, stream>>>(
        condbf, W1abf, batch, gbias, H1);
    stats_kernel<<<M_TOT / 128, 256, 0, stream>>>(H1, sums1);
    finalize_kernel<<<1, HID, 0, stream>>>(sums1, g1, be1, ss1);
    act_kernel<<<(M_TOT * HID / 8) / 256, 256, 0, stream>>>(H1, ss1);

    gemm_lds_kernel<HID, false><<<dim3(M_TOT / 128, HID / 128), 256, 0, stream>>>(
        H1, W2bf, batch, b2, H2);
    stats_kernel<<<M_TOT / 128, 256, 0, stream>>>(H2, sums2);
    finalize_kernel<<<1, HID, 0, stream>>>(sums2, g2, be2, ss2);
    g3_kernel<<<M_TOT / 32, 256, 0, stream>>>(H2, ss2, W3, b3, outf);
}

// Round 4
// 349.680 us; speedup vs baseline: 2.0050x; 1.1051x over previous
//
#include <hip/hip_runtime.h>
#include <hip/hip_bf16.h>
#include <math.h>
#include <stdint.h>

#define B_GRAPHS 64
#define N_NODES  2048
#define E_DIM    16
#define M_TOT    (B_GRAPHS * N_NODES)   // 131072
#define K_COND   64
#define MLP_IN   192
#define HID      512
#define POOLD    128
#define BN_EPS   1e-5f

typedef __attribute__((ext_vector_type(8))) short bfrag8;
typedef __attribute__((ext_vector_type(4))) float facc4;

__device__ __forceinline__ unsigned short f2b(float f) {
    unsigned int x = __builtin_bit_cast(unsigned int, f);
    unsigned int r = x + 0x7fffu + ((x >> 16) & 1u);
    return (unsigned short)(r >> 16);
}
__device__ __forceinline__ float b2f(unsigned short u) {
    unsigned int x = ((unsigned int)u) << 16;
    return __builtin_bit_cast(float, x);
}

// Branch-free GELU: erf via Abramowitz-Stegun 7.1.26 (|err| <= 1.5e-7).
__device__ __forceinline__ float gelu_fast(float y) {
    float x  = y * 0.70710678118654752440f;
    float ax = fabsf(x);
    float t  = __builtin_amdgcn_rcpf(fmaf(0.3275911f, ax, 1.0f));
    float p  = fmaf(1.061405429f, t, -1.453152027f);
    p = fmaf(p, t, 1.421413741f);
    p = fmaf(p, t, -0.284496736f);
    p = fmaf(p, t, 0.254829592f);
    p = p * t;
    float e = __expf(-x * x);
    float erfax = fmaf(-p, e, 1.0f);
    float erfx  = copysignf(erfax, x);
    return 0.5f * y * (1.0f + erfx);
}

#define GLOAD_LDS16(g, l)                                                        \
    __builtin_amdgcn_global_load_lds(                                            \
        (const __attribute__((address_space(1))) unsigned int*)(const void*)(g), \
        (__attribute__((address_space(3))) unsigned int*)(void*)(l), 16, 0, 0)

// ---------------- pool: x [131072,16] -> pooled [64,128] ----------------
__global__ void pool_kernel(const float* __restrict__ x, float* __restrict__ pooled) {
    int g = blockIdx.x;           // 64 blocks
    int t = threadIdx.x;          // 128 threads
    int h = t >> 2, w = t & 3;
    const float* base = x + (size_t)g * N_NODES * E_DIM + (size_t)h * 64 * E_DIM + w * 4;
    float s = 0.f;
    #pragma unroll 4
    for (int r = 0; r < 64; ++r) {
        float4 v = *reinterpret_cast<const float4*>(base + (size_t)r * E_DIM);
        s += v.x + v.y + v.z + v.w;
    }
    pooled[g * POOLD + h * 4 + w] = s * (1.0f / 256.0f);
}

// ------------- gbias[g][n] = pooled[g] . W1[n,64:192] + b1[n] -------------
__global__ void gbias_kernel(const float* __restrict__ pooled, const float* __restrict__ W1,
                             const float* __restrict__ b1, float* __restrict__ gbias) {
    int g = blockIdx.x;   // 64
    int n = threadIdx.x;  // 512
    const float* pr = pooled + g * POOLD;
    const float* wr = W1 + (size_t)n * MLP_IN + K_COND;
    float s = b1[n];
    #pragma unroll 4
    for (int k = 0; k < POOLD; ++k) s = fmaf(pr[k], wr[k], s);
    gbias[g * HID + n] = s;
}

// ------------- contiguous fp32 -> bf16 (for W2) -------------
__global__ __launch_bounds__(256) void cvt_kernel(const float* __restrict__ s,
                                                  unsigned short* __restrict__ d) {
    size_t i = ((size_t)blockIdx.x * 256 + threadIdx.x) * 8;
    float4 v0 = *reinterpret_cast<const float4*>(s + i);
    float4 v1 = *reinterpret_cast<const float4*>(s + i + 4);
    unsigned short t[8] = {f2b(v0.x), f2b(v0.y), f2b(v0.z), f2b(v0.w),
                           f2b(v1.x), f2b(v1.y), f2b(v1.z), f2b(v1.w)};
    *reinterpret_cast<bfrag8*>(d + i) = *reinterpret_cast<bfrag8*>(t);
}

__device__ __forceinline__ bfrag8 load_f32x8_as_bf16(const float* p) {
    float4 v0 = *reinterpret_cast<const float4*>(p);
    float4 v1 = *reinterpret_cast<const float4*>(p + 4);
    unsigned short t[8] = {f2b(v0.x), f2b(v0.y), f2b(v0.z), f2b(v0.w),
                           f2b(v1.x), f2b(v1.y), f2b(v1.z), f2b(v1.w)};
    return *reinterpret_cast<bfrag8*>(t);
}

// ------------- GEMM1: H1 = cond[.,0:64] @ W1[.,0:64]^T + gbias[batch], fused stats -------------
// 128x128 tile, 4 waves, NO LDS staging (K=64: fragments loaded directly from global).
__global__ __launch_bounds__(256) void gemm1_kernel(const float* __restrict__ A,
                                                    const float* __restrict__ W,
                                                    const int* __restrict__ batch,
                                                    const float* __restrict__ gbias,
                                                    float* __restrict__ sums,
                                                    unsigned short* __restrict__ C) {
    __shared__ float sArr[128], qArr[128];
    const int t = threadIdx.x;
    const int r0 = blockIdx.x * 128, c0 = blockIdx.y * 128;
    const int l = t & 63, w = t >> 6;
    const int wr = w >> 1, wc = w & 1;
    const int ln = l & 15, kg = l >> 4;
    if (t < 128) { sArr[t] = 0.f; qArr[t] = 0.f; }
    __syncthreads();

    facc4 acc[4][4];
    const facc4 z = {0.f, 0.f, 0.f, 0.f};
    #pragma unroll
    for (int a = 0; a < 4; ++a)
        #pragma unroll
        for (int b = 0; b < 4; ++b) acc[a][b] = z;

    #pragma unroll
    for (int ks = 0; ks < 2; ++ks) {
        bfrag8 af[4], bf[4];
        #pragma unroll
        for (int a = 0; a < 4; ++a)
            af[a] = load_f32x8_as_bf16(A + (size_t)(r0 + wr * 64 + a * 16 + ln) * K_COND + ks * 32 + kg * 8);
        #pragma unroll
        for (int b = 0; b < 4; ++b)
            bf[b] = load_f32x8_as_bf16(W + (size_t)(c0 + wc * 64 + b * 16 + ln) * MLP_IN + ks * 32 + kg * 8);
        #pragma unroll
        for (int a = 0; a < 4; ++a)
            #pragma unroll
            for (int b = 0; b < 4; ++b)
                acc[a][b] = __builtin_amdgcn_mfma_f32_16x16x32_bf16(af[a], bf[b], acc[a][b], 0, 0, 0);
    }

    float cs[4] = {0.f, 0.f, 0.f, 0.f}, cq[4] = {0.f, 0.f, 0.f, 0.f};
    #pragma unroll
    for (int a = 0; a < 4; ++a) {
        #pragma unroll
        for (int i = 0; i < 4; ++i) {
            int row = r0 + wr * 64 + a * 16 + kg * 4 + i;
            const float* gb = gbias + (size_t)batch[row] * HID;
            size_t rbase = (size_t)row * HID + c0 + wc * 64 + ln;
            #pragma unroll
            for (int b = 0; b < 4; ++b) {
                float v = acc[a][b][i] + gb[c0 + wc * 64 + b * 16 + ln];
                C[rbase + b * 16] = f2b(v);
                cs[b] += v; cq[b] = fmaf(v, v, cq[b]);
            }
        }
    }
    #pragma unroll
    for (int b = 0; b < 4; ++b) {
        cs[b] += __shfl_xor(cs[b], 16, 64); cq[b] += __shfl_xor(cq[b], 16, 64);
        cs[b] += __shfl_xor(cs[b], 32, 64); cq[b] += __shfl_xor(cq[b], 32, 64);
    }
    if (kg == 0) {
        #pragma unroll
        for (int b = 0; b < 4; ++b) {
            int cl = wc * 64 + b * 16 + ln;
            atomicAdd(&sArr[cl], cs[b]); atomicAdd(&qArr[cl], cq[b]);
        }
    }
    __syncthreads();
    if (t < 128) {
        atomicAdd(&sums[c0 + t], sArr[t]);
        atomicAdd(&sums[HID + c0 + t], qArr[t]);
    }
}

// ------------- GEMM2: H2 = gelu(bn(H1)) @ W2^T + b2, fused act1 + stats2 -------------
// 128x256 tile, 8 waves (2x4). A reg-staged with act applied; B via global_load_lds.
__global__ __launch_bounds__(512) void gemm2_kernel(const unsigned short* __restrict__ A,
                                                    const unsigned short* __restrict__ Bm,
                                                    const float* __restrict__ ssg,
                                                    const float* __restrict__ bias,
                                                    float* __restrict__ sums,
                                                    unsigned short* __restrict__ C) {
    __shared__ unsigned short As[128 * 32];   // 8KB
    __shared__ unsigned short Bs[256 * 32];   // 16KB
    __shared__ float lss[2 * HID];            // 4KB
    __shared__ float sArr[256], qArr[256];    // 2KB
    const int t = threadIdx.x;
    const int r0 = blockIdx.x * 128, c0 = blockIdx.y * 256;
    const int l = t & 63, w = t >> 6;         // 8 waves
    const int wr = w >> 2, wc = w & 3;
    const int ln = l & 15, kg = l >> 4;
    const int arow = t >> 2, aslot = t & 3;

    lss[t] = ssg[t];
    lss[t + 512] = ssg[t + 512];
    if (t < 256) { sArr[t] = 0.f; qArr[t] = 0.f; }
    __syncthreads();

    facc4 acc[4][4];
    const facc4 z = {0.f, 0.f, 0.f, 0.f};
    #pragma unroll
    for (int a = 0; a < 4; ++a)
        #pragma unroll
        for (int b = 0; b < 4; ++b) acc[a][b] = z;

    const unsigned short* aptr = A + (size_t)(r0 + arow) * HID + aslot * 8;
    for (int kk = 0; kk < HID; kk += 32) {
        // stage A: bf16 load -> BN affine + gelu -> LDS
        bfrag8 va = *reinterpret_cast<const bfrag8*>(aptr + kk);
        unsigned short tmp[8];
        #pragma unroll
        for (int j = 0; j < 8; ++j) {
            int col = kk + aslot * 8 + j;
            float xv = b2f((unsigned short)va[j]);
            float y = fmaf(xv, lss[col], lss[HID + col]);
            tmp[j] = f2b(gelu_fast(y));
        }
        *reinterpret_cast<bfrag8*>(&As[arow * 32 + aslot * 8]) = *reinterpret_cast<bfrag8*>(tmp);
        // stage B: 16 chunks of 16 rows via global_load_lds
        #pragma unroll
        for (int c = 0; c < 2; ++c) {
            int chunk = w * 2 + c;
            const unsigned short* gb =
                Bm + (size_t)(c0 + chunk * 16 + (l >> 2)) * HID + kk + (l & 3) * 8;
            GLOAD_LDS16(gb, &Bs[chunk * 512]);
        }
        __syncthreads();
        bfrag8 af[4], bf[4];
        #pragma unroll
        for (int a = 0; a < 4; ++a)
            af[a] = *reinterpret_cast<const bfrag8*>(&As[(wr * 64 + a * 16 + ln) * 32 + kg * 8]);
        #pragma unroll
        for (int b = 0; b < 4; ++b)
            bf[b] = *reinterpret_cast<const bfrag8*>(&Bs[(wc * 64 + b * 16 + ln) * 32 + kg * 8]);
        #pragma unroll
        for (int a = 0; a < 4; ++a)
            #pragma unroll
            for (int b = 0; b < 4; ++b)
                acc[a][b] = __builtin_amdgcn_mfma_f32_16x16x32_bf16(af[a], bf[b], acc[a][b], 0, 0, 0);
        __syncthreads();
    }

    float bb[4];
    #pragma unroll
    for (int b = 0; b < 4; ++b) bb[b] = bias[c0 + wc * 64 + b * 16 + ln];
    float cs[4] = {0.f, 0.f, 0.f, 0.f}, cq[4] = {0.f, 0.f, 0.f, 0.f};
    #pragma unroll
    for (int a = 0; a < 4; ++a) {
        #pragma unroll
        for (int i = 0; i < 4; ++i) {
            size_t rbase = (size_t)(r0 + wr * 64 + a * 16 + kg * 4 + i) * HID + c0 + wc * 64 + ln;
            #pragma unroll
            for (int b = 0; b < 4; ++b) {
                float v = acc[a][b][i] + bb[b];
                C[rbase + b * 16] = f2b(v);
                cs[b] += v; cq[b] = fmaf(v, v, cq[b]);
            }
        }
    }
    #pragma unroll
    for (int b = 0; b < 4; ++b) {
        cs[b] += __shfl_xor(cs[b], 16, 64); cq[b] += __shfl_xor(cq[b], 16, 64);
        cs[b] += __shfl_xor(cs[b], 32, 64); cq[b] += __shfl_xor(cq[b], 32, 64);
    }
    if (kg == 0) {
        #pragma unroll
        for (int b = 0; b < 4; ++b) {
            int cl = wc * 64 + b * 16 + ln;
            atomicAdd(&sArr[cl], cs[b]); atomicAdd(&qArr[cl], cq[b]);
        }
    }
    __syncthreads();
    if (t < 256) {
        atomicAdd(&sums[c0 + t], sArr[t]);
        atomicAdd(&sums[HID + c0 + t], qArr[t]);
    }
}

// ------------- finalize: ss[0:512]=scale, ss[512:1024]=shift -------------
__global__ void finalize_kernel(const float* __restrict__ sums, const float* __restrict__ g,
                                const float* __restrict__ be, float* __restrict__ ss) {
    int n = threadIdx.x;  // 512
    float mean = sums[n] * (1.0f / M_TOT);
    float var = sums[HID + n] * (1.0f / M_TOT) - mean * mean;
    float sc = g[n] * rsqrtf(var + BN_EPS);
    ss[n] = sc;
    ss[HID + n] = be[n] - mean * sc;
}

// ------------- G3: out[m][0:3] = gelu(bn(H2[m])) . W3^T + b3  (8 lanes per row) -------------
__global__ __launch_bounds__(256) void g3_kernel(const unsigned short* __restrict__ H2,
                                                 const float* __restrict__ ss2,
                                                 const float* __restrict__ W3,
                                                 const float* __restrict__ b3,
                                                 float* __restrict__ out) {
    int t = threadIdx.x;
    int l = t & 63, w = t >> 6;
    int rsub = l >> 3, lk = l & 7;
    int row = blockIdx.x * 32 + w * 8 + rsub;
    const unsigned short* p = H2 + (size_t)row * HID;
    float o0 = 0.f, o1 = 0.f, o2 = 0.f;
    #pragma unroll
    for (int it = 0; it < 8; ++it) {
        int k = it * 64 + lk * 8;
        bfrag8 v = *reinterpret_cast<const bfrag8*>(p + k);
        #pragma unroll
        for (int j = 0; j < 8; ++j) {
            float x = b2f((unsigned short)v[j]);
            float y = fmaf(x, ss2[k + j], ss2[HID + k + j]);
            y = gelu_fast(y);
            o0 = fmaf(y, W3[k + j], o0);
            o1 = fmaf(y, W3[HID + k + j], o1);
            o2 = fmaf(y, W3[2 * HID + k + j], o2);
        }
    }
    #pragma unroll
    for (int m = 1; m < 8; m <<= 1) {
        o0 += __shfl_xor(o0, m, 64);
        o1 += __shfl_xor(o1, m, 64);
        o2 += __shfl_xor(o2, m, 64);
    }
    if (lk == 0) {
        out[(size_t)row * 3 + 0] = o0 + b3[0];
        out[(size_t)row * 3 + 1] = o1 + b3[1];
        out[(size_t)row * 3 + 2] = o2 + b3[2];
    }
}

extern "C" void kernel_launch(void* const* d_in, const int* in_sizes, int n_in,
                              void* d_out, int out_size, void* d_ws, size_t ws_size,
                              hipStream_t stream) {
    const float* x     = (const float*)d_in[0];
    const int*   batch = (const int*)d_in[1];
    const float* cond  = (const float*)d_in[2];
    const float* W1    = (const float*)d_in[3];
    const float* b1    = (const float*)d_in[4];
    const float* g1    = (const float*)d_in[5];
    const float* be1   = (const float*)d_in[6];
    const float* W2    = (const float*)d_in[7];
    const float* b2    = (const float*)d_in[8];
    const float* g2    = (const float*)d_in[9];
    const float* be2   = (const float*)d_in[10];
    const float* W3    = (const float*)d_in[11];
    const float* b3    = (const float*)d_in[12];

    const size_t H_BYTES = (size_t)M_TOT * HID * 2;  // 134,217,728
    if (ws_size < 2 * H_BYTES) return;               // clean fail instead of OOB crash
    char* ws = (char*)d_ws;
    unsigned short* H1 = (unsigned short*)ws;
    unsigned short* H2 = (unsigned short*)(ws + H_BYTES);

    // Small scratch lives in d_out (1.5MB of floats) until g3 overwrites it.
    float* outf   = (float*)d_out;
    float* pooled = outf;                        // 8192 floats
    float* gbias  = pooled + B_GRAPHS * POOLD;   // 32768 floats
    float* sums1  = gbias + B_GRAPHS * HID;      // 1024 (sum | sumsq)
    float* sums2  = sums1 + 2 * HID;             // 1024
    float* ss1    = sums2 + 2 * HID;             // 1024
    unsigned short* W2bf = (unsigned short*)(ss1 + 2 * HID);  // 262144 shorts (512KB)
    // ss2 goes into the H1 region, dead once gemm2 has consumed H1.
    float* ss2 = (float*)ws;

    hipMemsetAsync(sums1, 0, 2 * 2 * HID * sizeof(float), stream);

    pool_kernel<<<B_GRAPHS, 128, 0, stream>>>(x, pooled);
    gbias_kernel<<<B_GRAPHS, HID, 0, stream>>>(pooled, W1, b1, gbias);
    cvt_kernel<<<(HID * HID / 8) / 256, 256, 0, stream>>>(W2, W2bf);

    gemm1_kernel<<<dim3(M_TOT / 128, HID / 128), 256, 0, stream>>>(
        cond, W1, batch, gbias, sums1, H1);
    finalize_kernel<<<1, HID, 0, stream>>>(sums1, g1, be1, ss1);

    gemm2_kernel<<<dim3(M_TOT / 128, HID / 256), 512, 0, stream>>>(
        H1, W2bf, ss1, b2, sums2, H2);
    finalize_kernel<<<1, HID, 0, stream>>>(sums2, g2, be2, ss2);

    g3_kernel<<<M_TOT / 32, 256, 0, stream>>>(H2, ss2, W3, b3, outf);
}

// Round 5
// 335.441 us; speedup vs baseline: 2.0902x; 1.0425x over previous
//
#include <hip/hip_runtime.h>
#include <hip/hip_bf16.h>
#include <math.h>
#include <stdint.h>

#define B_GRAPHS 64
#define N_NODES  2048
#define E_DIM    16
#define M_TOT    (B_GRAPHS * N_NODES)   // 131072
#define K_COND   64
#define MLP_IN   192
#define HID      512
#define POOLD    128
#define BN_EPS   1e-5f

typedef __attribute__((ext_vector_type(8))) short bfrag8;
typedef __attribute__((ext_vector_type(4))) float facc4;

__device__ __forceinline__ unsigned short f2b(float f) {
    unsigned int x = __builtin_bit_cast(unsigned int, f);
    unsigned int r = x + 0x7fffu + ((x >> 16) & 1u);
    return (unsigned short)(r >> 16);
}
__device__ __forceinline__ float b2f(unsigned short u) {
    unsigned int x = ((unsigned int)u) << 16;
    return __builtin_bit_cast(float, x);
}

// Branch-free GELU: erf via Abramowitz-Stegun 7.1.26 (|err| <= 1.5e-7).
__device__ __forceinline__ float gelu_fast(float y) {
    float x  = y * 0.70710678118654752440f;
    float ax = fabsf(x);
    float t  = __builtin_amdgcn_rcpf(fmaf(0.3275911f, ax, 1.0f));
    float p  = fmaf(1.061405429f, t, -1.453152027f);
    p = fmaf(p, t, 1.421413741f);
    p = fmaf(p, t, -0.284496736f);
    p = fmaf(p, t, 0.254829592f);
    p = p * t;
    float e = __expf(-x * x);
    float erfax = fmaf(-p, e, 1.0f);
    float erfx  = copysignf(erfax, x);
    return 0.5f * y * (1.0f + erfx);
}

#define GLOAD_LDS16(g, l)                                                        \
    __builtin_amdgcn_global_load_lds(                                            \
        (const __attribute__((address_space(1))) unsigned int*)(const void*)(g), \
        (__attribute__((address_space(3))) unsigned int*)(void*)(l), 16, 0, 0)

// ---------------- prep: pooled (LDS) -> gbias[g][n] = pooled . W1[n,64:192] + b1[n] ----------------
__global__ __launch_bounds__(512) void prep_kernel(const float* __restrict__ x,
                                                   const float* __restrict__ W1,
                                                   const float* __restrict__ b1,
                                                   float* __restrict__ gbias) {
    __shared__ float pl[POOLD];
    int g = blockIdx.x, t = threadIdx.x;
    if (t < 128) {
        int h = t >> 2, w = t & 3;
        const float* base = x + (size_t)g * N_NODES * E_DIM + (size_t)h * 64 * E_DIM + w * 4;
        float s = 0.f;
        #pragma unroll 4
        for (int r = 0; r < 64; ++r) {
            float4 v = *reinterpret_cast<const float4*>(base + (size_t)r * E_DIM);
            s += v.x + v.y + v.z + v.w;
        }
        pl[h * 4 + w] = s * (1.0f / 256.0f);
    }
    __syncthreads();
    const float* wr_ = W1 + (size_t)t * MLP_IN + K_COND;
    float s = b1[t];
    #pragma unroll 4
    for (int k = 0; k < POOLD; ++k) s = fmaf(pl[k], wr_[k], s);
    gbias[g * HID + t] = s;
}

// ------------- contiguous fp32 -> bf16 (for W2) -------------
__global__ __launch_bounds__(256) void cvt_kernel(const float* __restrict__ s,
                                                  unsigned short* __restrict__ d) {
    size_t i = ((size_t)blockIdx.x * 256 + threadIdx.x) * 8;
    float4 v0 = *reinterpret_cast<const float4*>(s + i);
    float4 v1 = *reinterpret_cast<const float4*>(s + i + 4);
    unsigned short t[8] = {f2b(v0.x), f2b(v0.y), f2b(v0.z), f2b(v0.w),
                           f2b(v1.x), f2b(v1.y), f2b(v1.z), f2b(v1.w)};
    *reinterpret_cast<bfrag8*>(d + i) = *reinterpret_cast<bfrag8*>(t);
}

__device__ __forceinline__ bfrag8 load_f32x8_as_bf16(const float* p) {
    float4 v0 = *reinterpret_cast<const float4*>(p);
    float4 v1 = *reinterpret_cast<const float4*>(p + 4);
    unsigned short t[8] = {f2b(v0.x), f2b(v0.y), f2b(v0.z), f2b(v0.w),
                           f2b(v1.x), f2b(v1.y), f2b(v1.z), f2b(v1.w)};
    return *reinterpret_cast<bfrag8*>(t);
}

// ------------- GEMM1: H1 = cond[.,0:64] @ W1[.,0:64]^T + gbias[batch], fused stats -------------
__global__ __launch_bounds__(256) void gemm1_kernel(const float* __restrict__ A,
                                                    const float* __restrict__ W,
                                                    const int* __restrict__ batch,
                                                    const float* __restrict__ gbias,
                                                    float* __restrict__ sums,
                                                    unsigned short* __restrict__ C) {
    __shared__ float sArr[128], qArr[128];
    const int t = threadIdx.x;
    const int r0 = blockIdx.x * 128, c0 = blockIdx.y * 128;
    const int l = t & 63, w = t >> 6;
    const int wr = w >> 1, wc = w & 1;
    const int ln = l & 15, kg = l >> 4;
    if (t < 128) { sArr[t] = 0.f; qArr[t] = 0.f; }
    __syncthreads();

    facc4 acc[4][4];
    const facc4 z = {0.f, 0.f, 0.f, 0.f};
    #pragma unroll
    for (int a = 0; a < 4; ++a)
        #pragma unroll
        for (int b = 0; b < 4; ++b) acc[a][b] = z;

    #pragma unroll
    for (int ks = 0; ks < 2; ++ks) {
        bfrag8 af[4], bf[4];
        #pragma unroll
        for (int a = 0; a < 4; ++a)
            af[a] = load_f32x8_as_bf16(A + (size_t)(r0 + wr * 64 + a * 16 + ln) * K_COND + ks * 32 + kg * 8);
        #pragma unroll
        for (int b = 0; b < 4; ++b)
            bf[b] = load_f32x8_as_bf16(W + (size_t)(c0 + wc * 64 + b * 16 + ln) * MLP_IN + ks * 32 + kg * 8);
        #pragma unroll
        for (int a = 0; a < 4; ++a)
            #pragma unroll
            for (int b = 0; b < 4; ++b)
                acc[a][b] = __builtin_amdgcn_mfma_f32_16x16x32_bf16(af[a], bf[b], acc[a][b], 0, 0, 0);
    }

    float cs[4] = {0.f, 0.f, 0.f, 0.f}, cq[4] = {0.f, 0.f, 0.f, 0.f};
    #pragma unroll
    for (int a = 0; a < 4; ++a) {
        #pragma unroll
        for (int i = 0; i < 4; ++i) {
            int row = r0 + wr * 64 + a * 16 + kg * 4 + i;
            const float* gb = gbias + (size_t)batch[row] * HID;
            size_t rbase = (size_t)row * HID + c0 + wc * 64 + ln;
            #pragma unroll
            for (int b = 0; b < 4; ++b) {
                float v = acc[a][b][i] + gb[c0 + wc * 64 + b * 16 + ln];
                C[rbase + b * 16] = f2b(v);
                cs[b] += v; cq[b] = fmaf(v, v, cq[b]);
            }
        }
    }
    #pragma unroll
    for (int b = 0; b < 4; ++b) {
        cs[b] += __shfl_xor(cs[b], 16, 64); cq[b] += __shfl_xor(cq[b], 16, 64);
        cs[b] += __shfl_xor(cs[b], 32, 64); cq[b] += __shfl_xor(cq[b], 32, 64);
    }
    if (kg == 0) {
        #pragma unroll
        for (int b = 0; b < 4; ++b) {
            int cl = wc * 64 + b * 16 + ln;
            atomicAdd(&sArr[cl], cs[b]); atomicAdd(&qArr[cl], cq[b]);
        }
    }
    __syncthreads();
    if (t < 128) {
        atomicAdd(&sums[c0 + t], sArr[t]);
        atomicAdd(&sums[HID + c0 + t], qArr[t]);
    }
}

// ------------- GEMM2: H2 = gelu(bn1(H1)) @ W2^T + b2, fused act1 + stats2 -------------
// 128x256 tile, 8 waves, double-buffered LDS, 1 barrier/K-step, XOR-swizzled granules.
__global__ __launch_bounds__(512) void gemm2_kernel(const unsigned short* __restrict__ A,
                                                    const unsigned short* __restrict__ Bm,
                                                    const float* __restrict__ sums1,
                                                    const float* __restrict__ g1,
                                                    const float* __restrict__ be1,
                                                    const float* __restrict__ bias,
                                                    float* __restrict__ sums,
                                                    unsigned short* __restrict__ C) {
    __shared__ unsigned short As[2][128 * 32];   // 16KB
    __shared__ unsigned short Bs[2][256 * 32];   // 32KB
    __shared__ float lss[2 * HID];               // 4KB
    __shared__ float sArr[256], qArr[256];       // 2KB
    const int t = threadIdx.x;
    const int r0 = blockIdx.x * 128, c0 = blockIdx.y * 256;
    const int l = t & 63, w = t >> 6;            // 8 waves
    const int wr = w >> 2, wc = w & 3;
    const int ln = l & 15, kg = l >> 4;
    const int arow = t >> 2, aslot = t & 3;
    const int rr = l >> 2, sp = l & 3;           // B staging: lane -> (row, swizzled slot)
    const int bss = sp ^ ((rr >> 1) & 3);        //   pre-swizzled source slot

    // BN1 scale/shift from raw sums (folds finalize1)
    {
        float mean = sums1[t] * (1.0f / M_TOT);
        float var  = sums1[HID + t] * (1.0f / M_TOT) - mean * mean;
        float sc   = g1[t] * rsqrtf(var + BN_EPS);
        lss[t] = sc;
        lss[HID + t] = be1[t] - mean * sc;
    }
    if (t < 256) { sArr[t] = 0.f; qArr[t] = 0.f; }

    facc4 acc[4][4];
    const facc4 z = {0.f, 0.f, 0.f, 0.f};
    #pragma unroll
    for (int a = 0; a < 4; ++a)
        #pragma unroll
        for (int b = 0; b < 4; ++b) acc[a][b] = z;

    const unsigned short* aptr = A + (size_t)(r0 + arow) * HID + aslot * 8;
    const int awslot = aslot ^ ((arow >> 1) & 3);  // A swizzled write slot

    __syncthreads();  // lss ready (also orders the sArr init)

    // prologue: stage tile 0 into buffer 0
    {
        bfrag8 va = *reinterpret_cast<const bfrag8*>(aptr);
        unsigned short tmp[8];
        #pragma unroll
        for (int j = 0; j < 8; ++j) {
            int col = aslot * 8 + j;
            float xv = b2f((unsigned short)va[j]);
            tmp[j] = f2b(gelu_fast(fmaf(xv, lss[col], lss[HID + col])));
        }
        *reinterpret_cast<bfrag8*>(&As[0][arow * 32 + awslot * 8]) = *reinterpret_cast<bfrag8*>(tmp);
        #pragma unroll
        for (int c = 0; c < 2; ++c) {
            int chunk = w * 2 + c;
            const unsigned short* gb = Bm + (size_t)(c0 + chunk * 16 + rr) * HID + bss * 8;
            GLOAD_LDS16(gb, &Bs[0][chunk * 512]);
        }
    }
    __syncthreads();  // full vmcnt/lgkm drain

    for (int step = 0; step < 16; ++step) {
        const int cur = step & 1;
        // 1) issue ds_reads of current fragments
        bfrag8 af[4], bf[4];
        #pragma unroll
        for (int a = 0; a < 4; ++a) {
            int RA = wr * 64 + a * 16 + ln;
            af[a] = *reinterpret_cast<const bfrag8*>(&As[cur][RA * 32 + (kg ^ ((RA >> 1) & 3)) * 8]);
        }
        #pragma unroll
        for (int b = 0; b < 4; ++b) {
            int RB = wc * 64 + b * 16 + ln;
            bf[b] = *reinterpret_cast<const bfrag8*>(&Bs[cur][RB * 32 + (kg ^ ((RB >> 1) & 3)) * 8]);
        }
        // 2) issue next-tile prefetch (B direct-to-LDS, A to regs)
        bfrag8 va;
        const bool pf = step < 15;
        if (pf) {
            const int kk = step * 32 + 32;
            va = *reinterpret_cast<const bfrag8*>(aptr + kk);
            #pragma unroll
            for (int c = 0; c < 2; ++c) {
                int chunk = w * 2 + c;
                const unsigned short* gb = Bm + (size_t)(c0 + chunk * 16 + rr) * HID + kk + bss * 8;
                GLOAD_LDS16(gb, &Bs[cur ^ 1][chunk * 512]);
            }
        }
        // 3) MFMA on current
        #pragma unroll
        for (int a = 0; a < 4; ++a)
            #pragma unroll
            for (int b = 0; b < 4; ++b)
                acc[a][b] = __builtin_amdgcn_mfma_f32_16x16x32_bf16(af[a], bf[b], acc[a][b], 0, 0, 0);
        // 4) act + ds_write next A tile
        if (pf) {
            const int kk = step * 32 + 32;
            unsigned short tmp[8];
            #pragma unroll
            for (int j = 0; j < 8; ++j) {
                int col = kk + aslot * 8 + j;
                float xv = b2f((unsigned short)va[j]);
                tmp[j] = f2b(gelu_fast(fmaf(xv, lss[col], lss[HID + col])));
            }
            *reinterpret_cast<bfrag8*>(&As[cur ^ 1][arow * 32 + awslot * 8]) = *reinterpret_cast<bfrag8*>(tmp);
        }
        __syncthreads();  // drains vmcnt (B) + lgkm (A writes); next buffer ready
    }

    float bb[4];
    #pragma unroll
    for (int b = 0; b < 4; ++b) bb[b] = bias[c0 + wc * 64 + b * 16 + ln];
    float cs[4] = {0.f, 0.f, 0.f, 0.f}, cq[4] = {0.f, 0.f, 0.f, 0.f};
    #pragma unroll
    for (int a = 0; a < 4; ++a) {
        #pragma unroll
        for (int i = 0; i < 4; ++i) {
            size_t rbase = (size_t)(r0 + wr * 64 + a * 16 + kg * 4 + i) * HID + c0 + wc * 64 + ln;
            #pragma unroll
            for (int b = 0; b < 4; ++b) {
                float v = acc[a][b][i] + bb[b];
                C[rbase + b * 16] = f2b(v);
                cs[b] += v; cq[b] = fmaf(v, v, cq[b]);
            }
        }
    }
    #pragma unroll
    for (int b = 0; b < 4; ++b) {
        cs[b] += __shfl_xor(cs[b], 16, 64); cq[b] += __shfl_xor(cq[b], 16, 64);
        cs[b] += __shfl_xor(cs[b], 32, 64); cq[b] += __shfl_xor(cq[b], 32, 64);
    }
    if (kg == 0) {
        #pragma unroll
        for (int b = 0; b < 4; ++b) {
            int cl = wc * 64 + b * 16 + ln;
            atomicAdd(&sArr[cl], cs[b]); atomicAdd(&qArr[cl], cq[b]);
        }
    }
    __syncthreads();
    if (t < 256) {
        atomicAdd(&sums[c0 + t], sArr[t]);
        atomicAdd(&sums[HID + c0 + t], qArr[t]);
    }
}

// ------------- finalize: ss[0:512]=scale, ss[512:1024]=shift -------------
__global__ void finalize_kernel(const float* __restrict__ sums, const float* __restrict__ g,
                                const float* __restrict__ be, float* __restrict__ ss) {
    int n = threadIdx.x;  // 512
    float mean = sums[n] * (1.0f / M_TOT);
    float var = sums[HID + n] * (1.0f / M_TOT) - mean * mean;
    float sc = g[n] * rsqrtf(var + BN_EPS);
    ss[n] = sc;
    ss[HID + n] = be[n] - mean * sc;
}

// ------------- G3: out[m][0:3] = gelu(bn2(H2[m])) . W3^T + b3  (8 lanes per row) -------------
__global__ __launch_bounds__(256) void g3_kernel(const unsigned short* __restrict__ H2,
                                                 const float* __restrict__ ss2,
                                                 const float* __restrict__ W3,
                                                 const float* __restrict__ b3,
                                                 float* __restrict__ out) {
    __shared__ float lss[2 * HID];
    __shared__ float lw3[3 * HID];
    int t = threadIdx.x;
    for (int i = t; i < 2 * HID; i += 256) lss[i] = ss2[i];
    for (int i = t; i < 3 * HID; i += 256) lw3[i] = W3[i];
    __syncthreads();
    int l = t & 63, w = t >> 6;
    int rsub = l >> 3, lk = l & 7;
    int row = blockIdx.x * 32 + w * 8 + rsub;
    const unsigned short* p = H2 + (size_t)row * HID;
    float o0 = 0.f, o1 = 0.f, o2 = 0.f;
    #pragma unroll
    for (int it = 0; it < 8; ++it) {
        int k = it * 64 + lk * 8;
        bfrag8 v = *reinterpret_cast<const bfrag8*>(p + k);
        #pragma unroll
        for (int j = 0; j < 8; ++j) {
            float x = b2f((unsigned short)v[j]);
            float y = fmaf(x, lss[k + j], lss[HID + k + j]);
            y = gelu_fast(y);
            o0 = fmaf(y, lw3[k + j], o0);
            o1 = fmaf(y, lw3[HID + k + j], o1);
            o2 = fmaf(y, lw3[2 * HID + k + j], o2);
        }
    }
    #pragma unroll
    for (int m = 1; m < 8; m <<= 1) {
        o0 += __shfl_xor(o0, m, 64);
        o1 += __shfl_xor(o1, m, 64);
        o2 += __shfl_xor(o2, m, 64);
    }
    if (lk == 0) {
        out[(size_t)row * 3 + 0] = o0 + b3[0];
        out[(size_t)row * 3 + 1] = o1 + b3[1];
        out[(size_t)row * 3 + 2] = o2 + b3[2];
    }
}

extern "C" void kernel_launch(void* const* d_in, const int* in_sizes, int n_in,
                              void* d_out, int out_size, void* d_ws, size_t ws_size,
                              hipStream_t stream) {
    const float* x     = (const float*)d_in[0];
    const int*   batch = (const int*)d_in[1];
    const float* cond  = (const float*)d_in[2];
    const float* W1    = (const float*)d_in[3];
    const float* b1    = (const float*)d_in[4];
    const float* g1    = (const float*)d_in[5];
    const float* be1   = (const float*)d_in[6];
    const float* W2    = (const float*)d_in[7];
    const float* b2    = (const float*)d_in[8];
    const float* g2    = (const float*)d_in[9];
    const float* be2   = (const float*)d_in[10];
    const float* W3    = (const float*)d_in[11];
    const float* b3    = (const float*)d_in[12];

    const size_t H_BYTES = (size_t)M_TOT * HID * 2;  // 134,217,728
    if (ws_size < 2 * H_BYTES) return;               // clean fail instead of OOB crash
    char* ws = (char*)d_ws;
    unsigned short* H1 = (unsigned short*)ws;
    unsigned short* H2 = (unsigned short*)(ws + H_BYTES);

    // Small scratch lives in d_out (1.57MB) until g3 overwrites it.
    float* outf   = (float*)d_out;
    float* gbias  = outf;                        // 32768 floats
    float* sums1  = gbias + B_GRAPHS * HID;      // 1024 (sum | sumsq)
    float* sums2  = sums1 + 2 * HID;             // 1024
    unsigned short* W2bf = (unsigned short*)(sums2 + 2 * HID);  // 262144 shorts (512KB)
    // ss2 lives in the H1 region: written by finalize AFTER gemm2 consumed H1,
    // read by g3 (which writes d_out — so it can't live in d_out).
    float* ss2 = (float*)ws;

    hipMemsetAsync(sums1, 0, 2 * 2 * HID * sizeof(float), stream);

    prep_kernel<<<B_GRAPHS, 512, 0, stream>>>(x, W1, b1, gbias);
    cvt_kernel<<<(HID * HID / 8) / 256, 256, 0, stream>>>(W2, W2bf);

    gemm1_kernel<<<dim3(M_TOT / 128, HID / 128), 256, 0, stream>>>(
        cond, W1, batch, gbias, sums1, H1);

    gemm2_kernel<<<dim3(M_TOT / 128, HID / 256), 512, 0, stream>>>(
        H1, W2bf, sums1, g1, be1, b2, sums2, H2);

    finalize_kernel<<<1, HID, 0, stream>>>(sums2, g2, be2, ss2);

    g3_kernel<<<M_TOT / 32, 256, 0, stream>>>(H2, ss2, W3, b3, outf);
}

// Round 6
// 313.268 us; speedup vs baseline: 2.2381x; 1.0708x over previous
//
#include <hip/hip_runtime.h>
#include <hip/hip_bf16.h>
#include <math.h>
#include <stdint.h>

#define B_GRAPHS 64
#define N_NODES  2048
#define E_DIM    16
#define M_TOT    (B_GRAPHS * N_NODES)   // 131072
#define K_COND   64
#define MLP_IN   192
#define HID      512
#define POOLD    128
#define BN_EPS   1e-5f

typedef __attribute__((ext_vector_type(8))) short bfrag8;
typedef __attribute__((ext_vector_type(4))) float facc4;

__device__ __forceinline__ unsigned short f2b(float f) {
    unsigned int x = __builtin_bit_cast(unsigned int, f);
    unsigned int r = x + 0x7fffu + ((x >> 16) & 1u);
    return (unsigned short)(r >> 16);
}
__device__ __forceinline__ float b2f(unsigned short u) {
    unsigned int x = ((unsigned int)u) << 16;
    return __builtin_bit_cast(float, x);
}

// Branch-free GELU: erf via Abramowitz-Stegun 7.1.26 (|err| <= 1.5e-7).
__device__ __forceinline__ float gelu_fast(float y) {
    float x  = y * 0.70710678118654752440f;
    float ax = fabsf(x);
    float t  = __builtin_amdgcn_rcpf(fmaf(0.3275911f, ax, 1.0f));
    float p  = fmaf(1.061405429f, t, -1.453152027f);
    p = fmaf(p, t, 1.421413741f);
    p = fmaf(p, t, -0.284496736f);
    p = fmaf(p, t, 0.254829592f);
    p = p * t;
    float e = __expf(-x * x);
    float erfax = fmaf(-p, e, 1.0f);
    float erfx  = copysignf(erfax, x);
    return 0.5f * y * (1.0f + erfx);
}

#define GLOAD_LDS16(g, l)                                                        \
    __builtin_amdgcn_global_load_lds(                                            \
        (const __attribute__((address_space(1))) unsigned int*)(const void*)(g), \
        (__attribute__((address_space(3))) unsigned int*)(void*)(l), 16, 0, 0)

// ---------------- prep: pooled (LDS) -> gbias[g][n] = pooled . W1[n,64:192] + b1[n] ----------------
__global__ __launch_bounds__(512) void prep_kernel(const float* __restrict__ x,
                                                   const float* __restrict__ W1,
                                                   const float* __restrict__ b1,
                                                   float* __restrict__ gbias) {
    __shared__ float pl[POOLD];
    int g = blockIdx.x, t = threadIdx.x;
    if (t < 128) {
        int h = t >> 2, w = t & 3;
        const float* base = x + (size_t)g * N_NODES * E_DIM + (size_t)h * 64 * E_DIM + w * 4;
        float s = 0.f;
        #pragma unroll 4
        for (int r = 0; r < 64; ++r) {
            float4 v = *reinterpret_cast<const float4*>(base + (size_t)r * E_DIM);
            s += v.x + v.y + v.z + v.w;
        }
        pl[h * 4 + w] = s * (1.0f / 256.0f);
    }
    __syncthreads();
    const float* wr_ = W1 + (size_t)t * MLP_IN + K_COND;
    float s = b1[t];
    #pragma unroll 4
    for (int k = 0; k < POOLD; ++k) s = fmaf(pl[k], wr_[k], s);
    gbias[g * HID + t] = s;
}

// ------------- contiguous fp32 -> bf16 (for W2) -------------
__global__ __launch_bounds__(256) void cvt_kernel(const float* __restrict__ s,
                                                  unsigned short* __restrict__ d) {
    size_t i = ((size_t)blockIdx.x * 256 + threadIdx.x) * 8;
    float4 v0 = *reinterpret_cast<const float4*>(s + i);
    float4 v1 = *reinterpret_cast<const float4*>(s + i + 4);
    unsigned short t[8] = {f2b(v0.x), f2b(v0.y), f2b(v0.z), f2b(v0.w),
                           f2b(v1.x), f2b(v1.y), f2b(v1.z), f2b(v1.w)};
    *reinterpret_cast<bfrag8*>(d + i) = *reinterpret_cast<bfrag8*>(t);
}

__device__ __forceinline__ bfrag8 load_f32x8_as_bf16(const float* p) {
    float4 v0 = *reinterpret_cast<const float4*>(p);
    float4 v1 = *reinterpret_cast<const float4*>(p + 4);
    unsigned short t[8] = {f2b(v0.x), f2b(v0.y), f2b(v0.z), f2b(v0.w),
                           f2b(v1.x), f2b(v1.y), f2b(v1.z), f2b(v1.w)};
    return *reinterpret_cast<bfrag8*>(t);
}

// ------------- GEMM1: H1 = cond[.,0:64] @ W1[.,0:64]^T + gbias[batch], fused stats -------------
__global__ __launch_bounds__(256) void gemm1_kernel(const float* __restrict__ A,
                                                    const float* __restrict__ W,
                                                    const int* __restrict__ batch,
                                                    const float* __restrict__ gbias,
                                                    float* __restrict__ sums,
                                                    unsigned short* __restrict__ C) {
    __shared__ float sArr[128], qArr[128];
    const int t = threadIdx.x;
    const int r0 = blockIdx.x * 128, c0 = blockIdx.y * 128;
    const int l = t & 63, w = t >> 6;
    const int wr = w >> 1, wc = w & 1;
    const int ln = l & 15, kg = l >> 4;
    if (t < 128) { sArr[t] = 0.f; qArr[t] = 0.f; }
    __syncthreads();

    facc4 acc[4][4];
    const facc4 z = {0.f, 0.f, 0.f, 0.f};
    #pragma unroll
    for (int a = 0; a < 4; ++a)
        #pragma unroll
        for (int b = 0; b < 4; ++b) acc[a][b] = z;

    #pragma unroll
    for (int ks = 0; ks < 2; ++ks) {
        bfrag8 af[4], bf[4];
        #pragma unroll
        for (int a = 0; a < 4; ++a)
            af[a] = load_f32x8_as_bf16(A + (size_t)(r0 + wr * 64 + a * 16 + ln) * K_COND + ks * 32 + kg * 8);
        #pragma unroll
        for (int b = 0; b < 4; ++b)
            bf[b] = load_f32x8_as_bf16(W + (size_t)(c0 + wc * 64 + b * 16 + ln) * MLP_IN + ks * 32 + kg * 8);
        #pragma unroll
        for (int a = 0; a < 4; ++a)
            #pragma unroll
            for (int b = 0; b < 4; ++b)
                acc[a][b] = __builtin_amdgcn_mfma_f32_16x16x32_bf16(af[a], bf[b], acc[a][b], 0, 0, 0);
    }

    float cs[4] = {0.f, 0.f, 0.f, 0.f}, cq[4] = {0.f, 0.f, 0.f, 0.f};
    #pragma unroll
    for (int a = 0; a < 4; ++a) {
        #pragma unroll
        for (int i = 0; i < 4; ++i) {
            int row = r0 + wr * 64 + a * 16 + kg * 4 + i;
            const float* gb = gbias + (size_t)batch[row] * HID;
            size_t rbase = (size_t)row * HID + c0 + wc * 64 + ln;
            #pragma unroll
            for (int b = 0; b < 4; ++b) {
                float v = acc[a][b][i] + gb[c0 + wc * 64 + b * 16 + ln];
                C[rbase + b * 16] = f2b(v);
                cs[b] += v; cq[b] = fmaf(v, v, cq[b]);
            }
        }
    }
    #pragma unroll
    for (int b = 0; b < 4; ++b) {
        cs[b] += __shfl_xor(cs[b], 16, 64); cq[b] += __shfl_xor(cq[b], 16, 64);
        cs[b] += __shfl_xor(cs[b], 32, 64); cq[b] += __shfl_xor(cq[b], 32, 64);
    }
    if (kg == 0) {
        #pragma unroll
        for (int b = 0; b < 4; ++b) {
            int cl = wc * 64 + b * 16 + ln;
            atomicAdd(&sArr[cl], cs[b]); atomicAdd(&qArr[cl], cq[b]);
        }
    }
    __syncthreads();
    if (t < 128) {
        atomicAdd(&sums[c0 + t], sArr[t]);
        atomicAdd(&sums[HID + c0 + t], qArr[t]);
    }
}

// ------------- GEMM2: H2 = gelu(bn1(H1)) @ W2^T + b2, fused act1 + stats2 -------------
// BM=128 x BN=512 (full width, act computed ONCE), 8 waves (2x4), wave tile 64x128,
// double-buffered LDS, 1 barrier/K-step, XOR-swizzled granules, 2-deep A reg prefetch.
__global__ __launch_bounds__(512, 2) void gemm2_kernel(const unsigned short* __restrict__ A,
                                                       const unsigned short* __restrict__ Bm,
                                                       const float* __restrict__ sums1,
                                                       const float* __restrict__ g1,
                                                       const float* __restrict__ be1,
                                                       const float* __restrict__ bias,
                                                       float* __restrict__ sums,
                                                       unsigned short* __restrict__ C) {
    __shared__ unsigned short As[2][128 * 32];   // 16KB
    __shared__ unsigned short Bs[2][512 * 32];   // 64KB
    __shared__ float lss[2 * HID];               // 4KB
    __shared__ float sArr[HID], qArr[HID];       // 4KB   (total 88KB)
    const int t = threadIdx.x;
    const int r0 = blockIdx.x * 128;
    const int l = t & 63, w = t >> 6;            // 8 waves
    const int wr = w >> 2, wc = w & 3;           // 2 x 4
    const int ln = l & 15, kg = l >> 4;
    const int arow = t >> 2, aslot = t & 3;
    const int awslot = aslot ^ ((arow >> 1) & 3);
    const int rr = l >> 2, sp = l & 3;
    const int bss = sp ^ ((rr >> 1) & 3);        // B pre-swizzled source slot

    // BN1 scale/shift from raw sums (folds finalize1)
    {
        float mean = sums1[t] * (1.0f / M_TOT);
        float var  = sums1[HID + t] * (1.0f / M_TOT) - mean * mean;
        float sc   = g1[t] * rsqrtf(var + BN_EPS);
        lss[t] = sc;
        lss[HID + t] = be1[t] - mean * sc;
    }
    sArr[t] = 0.f; qArr[t] = 0.f;

    facc4 acc[4][8];
    const facc4 z = {0.f, 0.f, 0.f, 0.f};
    #pragma unroll
    for (int a = 0; a < 4; ++a)
        #pragma unroll
        for (int b = 0; b < 8; ++b) acc[a][b] = z;

    const unsigned short* aptr = A + (size_t)(r0 + arow) * HID + aslot * 8;
    __syncthreads();  // lss + sArr ready

    // prologue: stage tile 0; prefetch A for step 1
    bfrag8 va_pending;
    {
        bfrag8 va0 = *reinterpret_cast<const bfrag8*>(aptr);
        unsigned short tmp[8];
        #pragma unroll
        for (int j = 0; j < 8; ++j) {
            int col = aslot * 8 + j;
            float xv = b2f((unsigned short)va0[j]);
            tmp[j] = f2b(gelu_fast(fmaf(xv, lss[col], lss[HID + col])));
        }
        *reinterpret_cast<bfrag8*>(&As[0][arow * 32 + awslot * 8]) = *reinterpret_cast<bfrag8*>(tmp);
        #pragma unroll
        for (int c = 0; c < 4; ++c) {
            int chunk = w * 4 + c;                          // 32 chunks x 16 rows
            const unsigned short* gb = Bm + (size_t)(chunk * 16 + rr) * HID + bss * 8;
            GLOAD_LDS16(gb, &Bs[0][chunk * 512]);
        }
        va_pending = *reinterpret_cast<const bfrag8*>(aptr + 32);
    }
    __syncthreads();

    #pragma unroll 2
    for (int step = 0; step < 16; ++step) {
        const int cur = step & 1, nxt = cur ^ 1;
        // 1) ds_reads of current fragments
        bfrag8 af[4], bf[8];
        #pragma unroll
        for (int a = 0; a < 4; ++a) {
            int RA = wr * 64 + a * 16 + ln;
            af[a] = *reinterpret_cast<const bfrag8*>(&As[cur][RA * 32 + (kg ^ ((RA >> 1) & 3)) * 8]);
        }
        #pragma unroll
        for (int b = 0; b < 8; ++b) {
            int RB = wc * 128 + b * 16 + ln;
            bf[b] = *reinterpret_cast<const bfrag8*>(&Bs[cur][RB * 32 + (kg ^ ((RB >> 1) & 3)) * 8]);
        }
        // 2) prefetch: B(step+1) -> LDS, A(step+2) -> regs
        if (step < 15) {
            const int kk = (step + 1) * 32;
            #pragma unroll
            for (int c = 0; c < 4; ++c) {
                int chunk = w * 4 + c;
                const unsigned short* gb = Bm + (size_t)(chunk * 16 + rr) * HID + kk + bss * 8;
                GLOAD_LDS16(gb, &Bs[nxt][chunk * 512]);
            }
        }
        bfrag8 va_future;
        if (step < 14) va_future = *reinterpret_cast<const bfrag8*>(aptr + (step + 2) * 32);
        // 3) MFMA on current
        #pragma unroll
        for (int a = 0; a < 4; ++a)
            #pragma unroll
            for (int b = 0; b < 8; ++b)
                acc[a][b] = __builtin_amdgcn_mfma_f32_16x16x32_bf16(af[a], bf[b], acc[a][b], 0, 0, 0);
        // 4) act + ds_write A(step+1)
        if (step < 15) {
            const int kk = (step + 1) * 32;
            unsigned short tmp[8];
            #pragma unroll
            for (int j = 0; j < 8; ++j) {
                int col = kk + aslot * 8 + j;
                float xv = b2f((unsigned short)va_pending[j]);
                tmp[j] = f2b(gelu_fast(fmaf(xv, lss[col], lss[HID + col])));
            }
            *reinterpret_cast<bfrag8*>(&As[nxt][arow * 32 + awslot * 8]) = *reinterpret_cast<bfrag8*>(tmp);
        }
        va_pending = va_future;
        __syncthreads();
    }

    float bb[8];
    #pragma unroll
    for (int b = 0; b < 8; ++b) bb[b] = bias[wc * 128 + b * 16 + ln];
    float cs[8], cq[8];
    #pragma unroll
    for (int b = 0; b < 8; ++b) { cs[b] = 0.f; cq[b] = 0.f; }
    #pragma unroll
    for (int a = 0; a < 4; ++a) {
        #pragma unroll
        for (int i = 0; i < 4; ++i) {
            size_t rbase = (size_t)(r0 + wr * 64 + a * 16 + kg * 4 + i) * HID + wc * 128 + ln;
            #pragma unroll
            for (int b = 0; b < 8; ++b) {
                float v = acc[a][b][i] + bb[b];
                C[rbase + b * 16] = f2b(v);
                cs[b] += v; cq[b] = fmaf(v, v, cq[b]);
            }
        }
    }
    #pragma unroll
    for (int b = 0; b < 8; ++b) {
        cs[b] += __shfl_xor(cs[b], 16, 64); cq[b] += __shfl_xor(cq[b], 16, 64);
        cs[b] += __shfl_xor(cs[b], 32, 64); cq[b] += __shfl_xor(cq[b], 32, 64);
    }
    if (kg == 0) {
        #pragma unroll
        for (int b = 0; b < 8; ++b) {
            int cl = wc * 128 + b * 16 + ln;
            atomicAdd(&sArr[cl], cs[b]); atomicAdd(&qArr[cl], cq[b]);
        }
    }
    __syncthreads();
    atomicAdd(&sums[t], sArr[t]);
    atomicAdd(&sums[HID + t], qArr[t]);
}

// ------------- finalize: ss[0:512]=scale, ss[512:1024]=shift -------------
__global__ void finalize_kernel(const float* __restrict__ sums, const float* __restrict__ g,
                                const float* __restrict__ be, float* __restrict__ ss) {
    int n = threadIdx.x;  // 512
    float mean = sums[n] * (1.0f / M_TOT);
    float var = sums[HID + n] * (1.0f / M_TOT) - mean * mean;
    float sc = g[n] * rsqrtf(var + BN_EPS);
    ss[n] = sc;
    ss[HID + n] = be[n] - mean * sc;
}

// ------------- G3: out[m][0:3] = gelu(bn2(H2[m])) . W3^T + b3  (8 lanes per row) -------------
__global__ __launch_bounds__(256) void g3_kernel(const unsigned short* __restrict__ H2,
                                                 const float* __restrict__ ss2,
                                                 const float* __restrict__ W3,
                                                 const float* __restrict__ b3,
                                                 float* __restrict__ out) {
    __shared__ float lss[2 * HID];
    __shared__ float lw3[3 * HID];
    int t = threadIdx.x;
    for (int i = t; i < 2 * HID; i += 256) lss[i] = ss2[i];
    for (int i = t; i < 3 * HID; i += 256) lw3[i] = W3[i];
    __syncthreads();
    int l = t & 63, w = t >> 6;
    int rsub = l >> 3, lk = l & 7;
    int row = blockIdx.x * 32 + w * 8 + rsub;
    const unsigned short* p = H2 + (size_t)row * HID;
    float o0 = 0.f, o1 = 0.f, o2 = 0.f;
    #pragma unroll
    for (int it = 0; it < 8; ++it) {
        int k = it * 64 + lk * 8;
        bfrag8 v = *reinterpret_cast<const bfrag8*>(p + k);
        #pragma unroll
        for (int j = 0; j < 8; ++j) {
            float x = b2f((unsigned short)v[j]);
            float y = fmaf(x, lss[k + j], lss[HID + k + j]);
            y = gelu_fast(y);
            o0 = fmaf(y, lw3[k + j], o0);
            o1 = fmaf(y, lw3[HID + k + j], o1);
            o2 = fmaf(y, lw3[2 * HID + k + j], o2);
        }
    }
    #pragma unroll
    for (int m = 1; m < 8; m <<= 1) {
        o0 += __shfl_xor(o0, m, 64);
        o1 += __shfl_xor(o1, m, 64);
        o2 += __shfl_xor(o2, m, 64);
    }
    if (lk == 0) {
        out[(size_t)row * 3 + 0] = o0 + b3[0];
        out[(size_t)row * 3 + 1] = o1 + b3[1];
        out[(size_t)row * 3 + 2] = o2 + b3[2];
    }
}

extern "C" void kernel_launch(void* const* d_in, const int* in_sizes, int n_in,
                              void* d_out, int out_size, void* d_ws, size_t ws_size,
                              hipStream_t stream) {
    const float* x     = (const float*)d_in[0];
    const int*   batch = (const int*)d_in[1];
    const float* cond  = (const float*)d_in[2];
    const float* W1    = (const float*)d_in[3];
    const float* b1    = (const float*)d_in[4];
    const float* g1    = (const float*)d_in[5];
    const float* be1   = (const float*)d_in[6];
    const float* W2    = (const float*)d_in[7];
    const float* b2    = (const float*)d_in[8];
    const float* g2    = (const float*)d_in[9];
    const float* be2   = (const float*)d_in[10];
    const float* W3    = (const float*)d_in[11];
    const float* b3    = (const float*)d_in[12];

    const size_t H_BYTES = (size_t)M_TOT * HID * 2;  // 134,217,728
    if (ws_size < 2 * H_BYTES) return;               // clean fail instead of OOB crash
    char* ws = (char*)d_ws;
    unsigned short* H1 = (unsigned short*)ws;
    unsigned short* H2 = (unsigned short*)(ws + H_BYTES);

    // Small scratch lives in d_out (1.57MB) until g3 overwrites it.
    float* outf   = (float*)d_out;
    float* gbias  = outf;                        // 32768 floats
    float* sums1  = gbias + B_GRAPHS * HID;      // 1024 (sum | sumsq)
    float* sums2  = sums1 + 2 * HID;             // 1024
    unsigned short* W2bf = (unsigned short*)(sums2 + 2 * HID);  // 262144 shorts (512KB)
    // ss2 lives in the H1 region: written by finalize AFTER gemm2 consumed H1,
    // read by g3 (which writes d_out — so it can't live in d_out).
    float* ss2 = (float*)ws;

    hipMemsetAsync(sums1, 0, 2 * 2 * HID * sizeof(float), stream);

    prep_kernel<<<B_GRAPHS, 512, 0, stream>>>(x, W1, b1, gbias);
    cvt_kernel<<<(HID * HID / 8) / 256, 256, 0, stream>>>(W2, W2bf);

    gemm1_kernel<<<dim3(M_TOT / 128, HID / 128), 256, 0, stream>>>(
        cond, W1, batch, gbias, sums1, H1);

    gemm2_kernel<<<dim3(M_TOT / 128, 1), 512, 0, stream>>>(
        H1, W2bf, sums1, g1, be1, b2, sums2, H2);

    finalize_kernel<<<1, HID, 0, stream>>>(sums2, g2, be2, ss2);

    g3_kernel<<<M_TOT / 32, 256, 0, stream>>>(H2, ss2, W3, b3, outf);
}

// Round 7
// 297.799 us; speedup vs baseline: 2.3544x; 1.0519x over previous
//
#include <hip/hip_runtime.h>
#include <hip/hip_bf16.h>
#include <math.h>
#include <stdint.h>

#define B_GRAPHS 64
#define N_NODES  2048
#define E_DIM    16
#define M_TOT    (B_GRAPHS * N_NODES)   // 131072
#define K_COND   64
#define MLP_IN   192
#define HID      512
#define POOLD    128
#define BN_EPS   1e-5f

typedef __attribute__((ext_vector_type(8))) short bfrag8;
typedef __attribute__((ext_vector_type(4))) float facc4;

__device__ __forceinline__ unsigned short f2b(float f) {
    unsigned int x = __builtin_bit_cast(unsigned int, f);
    unsigned int r = x + 0x7fffu + ((x >> 16) & 1u);
    return (unsigned short)(r >> 16);
}
__device__ __forceinline__ float b2f(unsigned short u) {
    unsigned int x = ((unsigned int)u) << 16;
    return __builtin_bit_cast(float, x);
}

// Branch-free GELU: erf via Abramowitz-Stegun 7.1.26 (|err| <= 1.5e-7).
__device__ __forceinline__ float gelu_fast(float y) {
    float x  = y * 0.70710678118654752440f;
    float ax = fabsf(x);
    float t  = __builtin_amdgcn_rcpf(fmaf(0.3275911f, ax, 1.0f));
    float p  = fmaf(1.061405429f, t, -1.453152027f);
    p = fmaf(p, t, 1.421413741f);
    p = fmaf(p, t, -0.284496736f);
    p = fmaf(p, t, 0.254829592f);
    p = p * t;
    float e = __expf(-x * x);
    float erfax = fmaf(-p, e, 1.0f);
    float erfx  = copysignf(erfax, x);
    return 0.5f * y * (1.0f + erfx);
}

#define GLOAD_LDS16(g, l)                                                        \
    __builtin_amdgcn_global_load_lds(                                            \
        (const __attribute__((address_space(1))) unsigned int*)(const void*)(g), \
        (__attribute__((address_space(3))) unsigned int*)(void*)(l), 16, 0, 0)

// ---------------- prep: pooled (LDS) -> gbias[g][n] = pooled . W1[n,64:192] + b1[n] ----------------
__global__ __launch_bounds__(512) void prep_kernel(const float* __restrict__ x,
                                                   const float* __restrict__ W1,
                                                   const float* __restrict__ b1,
                                                   float* __restrict__ gbias) {
    __shared__ float pl[POOLD];
    int g = blockIdx.x, t = threadIdx.x;
    if (t < 128) {
        int h = t >> 2, w = t & 3;
        const float* base = x + (size_t)g * N_NODES * E_DIM + (size_t)h * 64 * E_DIM + w * 4;
        float s = 0.f;
        #pragma unroll 4
        for (int r = 0; r < 64; ++r) {
            float4 v = *reinterpret_cast<const float4*>(base + (size_t)r * E_DIM);
            s += v.x + v.y + v.z + v.w;
        }
        pl[h * 4 + w] = s * (1.0f / 256.0f);
    }
    __syncthreads();
    const float* wr_ = W1 + (size_t)t * MLP_IN + K_COND;
    float s = b1[t];
    #pragma unroll 4
    for (int k = 0; k < POOLD; ++k) s = fmaf(pl[k], wr_[k], s);
    gbias[g * HID + t] = s;
}

// ------------- contiguous fp32 -> bf16 (for W2) -------------
__global__ __launch_bounds__(256) void cvt_kernel(const float* __restrict__ s,
                                                  unsigned short* __restrict__ d) {
    size_t i = ((size_t)blockIdx.x * 256 + threadIdx.x) * 8;
    float4 v0 = *reinterpret_cast<const float4*>(s + i);
    float4 v1 = *reinterpret_cast<const float4*>(s + i + 4);
    unsigned short t[8] = {f2b(v0.x), f2b(v0.y), f2b(v0.z), f2b(v0.w),
                           f2b(v1.x), f2b(v1.y), f2b(v1.z), f2b(v1.w)};
    *reinterpret_cast<bfrag8*>(d + i) = *reinterpret_cast<bfrag8*>(t);
}

__device__ __forceinline__ bfrag8 load_f32x8_as_bf16(const float* p) {
    float4 v0 = *reinterpret_cast<const float4*>(p);
    float4 v1 = *reinterpret_cast<const float4*>(p + 4);
    unsigned short t[8] = {f2b(v0.x), f2b(v0.y), f2b(v0.z), f2b(v0.w),
                           f2b(v1.x), f2b(v1.y), f2b(v1.z), f2b(v1.w)};
    return *reinterpret_cast<bfrag8*>(t);
}

// ------------- GEMM1: H1 = cond[.,0:64] @ W1[.,0:64]^T + gbias[row>>11], fused stats -------------
// BM=128 x BN=512 full width (grid.y=1, cond read once), 8 waves (2x4), no LDS staging.
__global__ __launch_bounds__(512, 2) void gemm1_kernel(const float* __restrict__ A,
                                                       const float* __restrict__ W,
                                                       const float* __restrict__ gbias,
                                                       float* __restrict__ sums,
                                                       unsigned short* __restrict__ C) {
    __shared__ float sArr[HID], qArr[HID];
    const int t = threadIdx.x;
    const int r0 = blockIdx.x * 128;
    const int g = r0 >> 11;              // batch id (sorted repeat: row/2048)
    const int l = t & 63, w = t >> 6;
    const int wr = w >> 2, wc = w & 3;   // 2 x 4 waves
    const int ln = l & 15, kg = l >> 4;
    sArr[t] = 0.f; qArr[t] = 0.f;
    __syncthreads();

    facc4 acc[4][8];
    const facc4 z = {0.f, 0.f, 0.f, 0.f};
    #pragma unroll
    for (int a = 0; a < 4; ++a)
        #pragma unroll
        for (int b = 0; b < 8; ++b) acc[a][b] = z;

    #pragma unroll
    for (int ks = 0; ks < 2; ++ks) {
        bfrag8 af[4], bf[8];
        #pragma unroll
        for (int a = 0; a < 4; ++a)
            af[a] = load_f32x8_as_bf16(A + (size_t)(r0 + wr * 64 + a * 16 + ln) * K_COND + ks * 32 + kg * 8);
        #pragma unroll
        for (int b = 0; b < 8; ++b)
            bf[b] = load_f32x8_as_bf16(W + (size_t)(wc * 128 + b * 16 + ln) * MLP_IN + ks * 32 + kg * 8);
        #pragma unroll
        for (int a = 0; a < 4; ++a)
            #pragma unroll
            for (int b = 0; b < 8; ++b)
                acc[a][b] = __builtin_amdgcn_mfma_f32_16x16x32_bf16(af[a], bf[b], acc[a][b], 0, 0, 0);
    }

    const float* gb = gbias + (size_t)g * HID;
    float gbv[8];
    #pragma unroll
    for (int b = 0; b < 8; ++b) gbv[b] = gb[wc * 128 + b * 16 + ln];
    float cs[8], cq[8];
    #pragma unroll
    for (int b = 0; b < 8; ++b) { cs[b] = 0.f; cq[b] = 0.f; }
    #pragma unroll
    for (int a = 0; a < 4; ++a) {
        #pragma unroll
        for (int i = 0; i < 4; ++i) {
            size_t rbase = (size_t)(r0 + wr * 64 + a * 16 + kg * 4 + i) * HID + wc * 128 + ln;
            #pragma unroll
            for (int b = 0; b < 8; ++b) {
                float v = acc[a][b][i] + gbv[b];
                C[rbase + b * 16] = f2b(v);
                cs[b] += v; cq[b] = fmaf(v, v, cq[b]);
            }
        }
    }
    #pragma unroll
    for (int b = 0; b < 8; ++b) {
        cs[b] += __shfl_xor(cs[b], 16, 64); cq[b] += __shfl_xor(cq[b], 16, 64);
        cs[b] += __shfl_xor(cs[b], 32, 64); cq[b] += __shfl_xor(cq[b], 32, 64);
    }
    if (kg == 0) {
        #pragma unroll
        for (int b = 0; b < 8; ++b) {
            int cl = wc * 128 + b * 16 + ln;
            atomicAdd(&sArr[cl], cs[b]); atomicAdd(&qArr[cl], cq[b]);
        }
    }
    __syncthreads();
    atomicAdd(&sums[t], sArr[t]);
    atomicAdd(&sums[HID + t], qArr[t]);
}

// ------------- GEMM2: H2 = gelu(bn1(H1)) @ W2^T + b2, fused act1 + stats2 -------------
// BM=128 x BN=512, 8 waves, double-buffered LDS, counted-vmcnt + dual raw-barrier
// pipeline (loads stay in flight across barriers), XOR-swizzled granules.
__global__ __launch_bounds__(512, 2) void gemm2_kernel(const unsigned short* __restrict__ A,
                                                       const unsigned short* __restrict__ Bm,
                                                       const float* __restrict__ sums1,
                                                       const float* __restrict__ g1,
                                                       const float* __restrict__ be1,
                                                       const float* __restrict__ bias,
                                                       float* __restrict__ sums,
                                                       unsigned short* __restrict__ C) {
    __shared__ unsigned short As[2][128 * 32];   // 16KB
    __shared__ unsigned short Bs[2][512 * 32];   // 64KB
    __shared__ float lss[2 * HID];               // 4KB
    __shared__ float sArr[HID], qArr[HID];       // 4KB   (total 88KB -> 1 block/CU)
    const int t = threadIdx.x;
    const int r0 = blockIdx.x * 128;
    const int l = t & 63, w = t >> 6;            // 8 waves
    const int wr = w >> 2, wc = w & 3;           // 2 x 4
    const int ln = l & 15, kg = l >> 4;
    const int arow = t >> 2, aslot = t & 3;
    const int awslot = aslot ^ ((arow >> 1) & 3);
    const int rr = l >> 2, sp = l & 3;
    const int bss = sp ^ ((rr >> 1) & 3);        // B pre-swizzled source slot

    // BN1 scale/shift from raw sums (folds finalize1)
    {
        float mean = sums1[t] * (1.0f / M_TOT);
        float var  = sums1[HID + t] * (1.0f / M_TOT) - mean * mean;
        float sc   = g1[t] * rsqrtf(var + BN_EPS);
        lss[t] = sc;
        lss[HID + t] = be1[t] - mean * sc;
    }
    sArr[t] = 0.f; qArr[t] = 0.f;

    facc4 acc[4][8];
    const facc4 z = {0.f, 0.f, 0.f, 0.f};
    #pragma unroll
    for (int a = 0; a < 4; ++a)
        #pragma unroll
        for (int b = 0; b < 8; ++b) acc[a][b] = z;

    const unsigned short* aptr = A + (size_t)(r0 + arow) * HID + aslot * 8;

    auto actwrite = [&](bfrag8 va, int kk, int buf) {
        unsigned short tmp[8];
        #pragma unroll
        for (int j = 0; j < 8; ++j) {
            int col = kk + aslot * 8 + j;
            float xv = b2f((unsigned short)va[j]);
            tmp[j] = f2b(gelu_fast(fmaf(xv, lss[col], lss[HID + col])));
        }
        *reinterpret_cast<bfrag8*>(&As[buf][arow * 32 + awslot * 8]) = *reinterpret_cast<bfrag8*>(tmp);
    };
    auto stageB = [&](int kk, int buf) {
        #pragma unroll
        for (int c = 0; c < 4; ++c) {
            int chunk = w * 4 + c;                // 32 chunks x 16 rows
            const unsigned short* gb = Bm + (size_t)(chunk * 16 + rr) * HID + kk + bss * 8;
            GLOAD_LDS16(gb, &Bs[buf][chunk * 512]);
        }
    };
    auto dsread = [&](bfrag8* af, bfrag8* bf, int buf) {
        #pragma unroll
        for (int a = 0; a < 4; ++a) {
            int RA = wr * 64 + a * 16 + ln;
            af[a] = *reinterpret_cast<const bfrag8*>(&As[buf][RA * 32 + (kg ^ ((RA >> 1) & 3)) * 8]);
        }
        #pragma unroll
        for (int b = 0; b < 8; ++b) {
            int RB = wc * 128 + b * 16 + ln;
            bf[b] = *reinterpret_cast<const bfrag8*>(&Bs[buf][RB * 32 + (kg ^ ((RB >> 1) & 3)) * 8]);
        }
    };
    auto domfma = [&](bfrag8* af, bfrag8* bf) {
        #pragma unroll
        for (int a = 0; a < 4; ++a)
            #pragma unroll
            for (int b = 0; b < 8; ++b)
                acc[a][b] = __builtin_amdgcn_mfma_f32_16x16x32_bf16(af[a], bf[b], acc[a][b], 0, 0, 0);
    };

    __syncthreads();  // lss/sArr ready (full drain: vmem queue empty at loop entry)

    // prologue — queue: [AL0, B0x4, AL1, B1x4]
    bfrag8 va_p, va_q;
    va_p = *reinterpret_cast<const bfrag8*>(aptr);          // AL0
    stageB(0, 0);                                           // B0
    va_q = *reinterpret_cast<const bfrag8*>(aptr + 32);     // AL1
    stageB(32, 1);                                          // B1
    asm volatile("s_waitcnt vmcnt(9)" ::: "memory");        // retire AL0
    actwrite(va_p, 0, 0);
    va_p = va_q;
    asm volatile("s_waitcnt lgkmcnt(0)" ::: "memory");

    bfrag8 af[4], bf[8];
    #pragma unroll 2
    for (int tt = 0; tt < 14; ++tt) {
        const int cur = tt & 1, nxt = cur ^ 1;
        // retire B(tt)x4 + AL(tt+1); keep B(tt+1)x4 in flight
        asm volatile("s_waitcnt vmcnt(4)" ::: "memory");
        __builtin_amdgcn_s_barrier();
        __builtin_amdgcn_sched_barrier(0);
        dsread(af, bf, cur);
        actwrite(va_p, (tt + 1) * 32, nxt);
        asm volatile("s_waitcnt lgkmcnt(0)" ::: "memory");  // my reads in regs, my A-write done
        __builtin_amdgcn_s_barrier();                        // all waves done reading [cur]
        __builtin_amdgcn_sched_barrier(0);
        va_q = *reinterpret_cast<const bfrag8*>(aptr + (tt + 2) * 32);  // AL(tt+2)
        stageB((tt + 2) * 32, cur);                                      // B(tt+2) -> [cur]
        domfma(af, bf);
        va_p = va_q;
    }
    {   // tt = 14 (cur=0): no more issues
        asm volatile("s_waitcnt vmcnt(4)" ::: "memory");    // retire B14x4 + AL15
        __builtin_amdgcn_s_barrier();
        __builtin_amdgcn_sched_barrier(0);
        dsread(af, bf, 0);
        actwrite(va_p, 15 * 32, 1);
        asm volatile("s_waitcnt lgkmcnt(0)" ::: "memory");
        __builtin_amdgcn_s_barrier();
        __builtin_amdgcn_sched_barrier(0);
        domfma(af, bf);
    }
    {   // tt = 15 (cur=1)
        asm volatile("s_waitcnt vmcnt(0)" ::: "memory");    // retire B15x4
        __builtin_amdgcn_s_barrier();
        __builtin_amdgcn_sched_barrier(0);
        dsread(af, bf, 1);
        asm volatile("s_waitcnt lgkmcnt(0)" ::: "memory");
        domfma(af, bf);
    }

    float bb[8];
    #pragma unroll
    for (int b = 0; b < 8; ++b) bb[b] = bias[wc * 128 + b * 16 + ln];
    float cs[8], cq[8];
    #pragma unroll
    for (int b = 0; b < 8; ++b) { cs[b] = 0.f; cq[b] = 0.f; }
    #pragma unroll
    for (int a = 0; a < 4; ++a) {
        #pragma unroll
        for (int i = 0; i < 4; ++i) {
            size_t rbase = (size_t)(r0 + wr * 64 + a * 16 + kg * 4 + i) * HID + wc * 128 + ln;
            #pragma unroll
            for (int b = 0; b < 8; ++b) {
                float v = acc[a][b][i] + bb[b];
                C[rbase + b * 16] = f2b(v);
                cs[b] += v; cq[b] = fmaf(v, v, cq[b]);
            }
        }
    }
    #pragma unroll
    for (int b = 0; b < 8; ++b) {
        cs[b] += __shfl_xor(cs[b], 16, 64); cq[b] += __shfl_xor(cq[b], 16, 64);
        cs[b] += __shfl_xor(cs[b], 32, 64); cq[b] += __shfl_xor(cq[b], 32, 64);
    }
    if (kg == 0) {
        #pragma unroll
        for (int b = 0; b < 8; ++b) {
            int cl = wc * 128 + b * 16 + ln;
            atomicAdd(&sArr[cl], cs[b]); atomicAdd(&qArr[cl], cq[b]);
        }
    }
    __syncthreads();
    atomicAdd(&sums[t], sArr[t]);
    atomicAdd(&sums[HID + t], qArr[t]);
}

// ------------- finalize: ss[0:512]=scale, ss[512:1024]=shift -------------
__global__ void finalize_kernel(const float* __restrict__ sums, const float* __restrict__ g,
                                const float* __restrict__ be, float* __restrict__ ss) {
    int n = threadIdx.x;  // 512
    float mean = sums[n] * (1.0f / M_TOT);
    float var = sums[HID + n] * (1.0f / M_TOT) - mean * mean;
    float sc = g[n] * rsqrtf(var + BN_EPS);
    ss[n] = sc;
    ss[HID + n] = be[n] - mean * sc;
}

// ------------- G3: out[m][0:3] = gelu(bn2(H2[m])) . W3^T + b3  (8 lanes per row) -------------
__global__ __launch_bounds__(256) void g3_kernel(const unsigned short* __restrict__ H2,
                                                 const float* __restrict__ ss2,
                                                 const float* __restrict__ W3,
                                                 const float* __restrict__ b3,
                                                 float* __restrict__ out) {
    __shared__ float lss[2 * HID];
    __shared__ float lw3[3 * HID];
    int t = threadIdx.x;
    for (int i = t; i < 2 * HID; i += 256) lss[i] = ss2[i];
    for (int i = t; i < 3 * HID; i += 256) lw3[i] = W3[i];
    __syncthreads();
    int l = t & 63, w = t >> 6;
    int rsub = l >> 3, lk = l & 7;
    int row = blockIdx.x * 32 + w * 8 + rsub;
    const unsigned short* p = H2 + (size_t)row * HID;
    float o0 = 0.f, o1 = 0.f, o2 = 0.f;
    #pragma unroll
    for (int it = 0; it < 8; ++it) {
        int k = it * 64 + lk * 8;
        bfrag8 v = *reinterpret_cast<const bfrag8*>(p + k);
        #pragma unroll
        for (int j = 0; j < 8; ++j) {
            float x = b2f((unsigned short)v[j]);
            float y = fmaf(x, lss[k + j], lss[HID + k + j]);
            y = gelu_fast(y);
            o0 = fmaf(y, lw3[k + j], o0);
            o1 = fmaf(y, lw3[HID + k + j], o1);
            o2 = fmaf(y, lw3[2 * HID + k + j], o2);
        }
    }
    #pragma unroll
    for (int m = 1; m < 8; m <<= 1) {
        o0 += __shfl_xor(o0, m, 64);
        o1 += __shfl_xor(o1, m, 64);
        o2 += __shfl_xor(o2, m, 64);
    }
    if (lk == 0) {
        out[(size_t)row * 3 + 0] = o0 + b3[0];
        out[(size_t)row * 3 + 1] = o1 + b3[1];
        out[(size_t)row * 3 + 2] = o2 + b3[2];
    }
}

extern "C" void kernel_launch(void* const* d_in, const int* in_sizes, int n_in,
                              void* d_out, int out_size, void* d_ws, size_t ws_size,
                              hipStream_t stream) {
    const float* x     = (const float*)d_in[0];
    const float* cond  = (const float*)d_in[2];
    const float* W1    = (const float*)d_in[3];
    const float* b1    = (const float*)d_in[4];
    const float* g1    = (const float*)d_in[5];
    const float* be1   = (const float*)d_in[6];
    const float* W2    = (const float*)d_in[7];
    const float* b2    = (const float*)d_in[8];
    const float* g2    = (const float*)d_in[9];
    const float* be2   = (const float*)d_in[10];
    const float* W3    = (const float*)d_in[11];
    const float* b3    = (const float*)d_in[12];

    const size_t H_BYTES = (size_t)M_TOT * HID * 2;  // 134,217,728
    if (ws_size < 2 * H_BYTES) return;               // clean fail instead of OOB crash
    char* ws = (char*)d_ws;
    unsigned short* H1 = (unsigned short*)ws;
    unsigned short* H2 = (unsigned short*)(ws + H_BYTES);

    // Small scratch lives in d_out (1.57MB) until g3 overwrites it.
    float* outf   = (float*)d_out;
    float* gbias  = outf;                        // 32768 floats
    float* sums1  = gbias + B_GRAPHS * HID;      // 1024 (sum | sumsq)
    float* sums2  = sums1 + 2 * HID;             // 1024
    unsigned short* W2bf = (unsigned short*)(sums2 + 2 * HID);  // 262144 shorts (512KB)
    // ss2 lives in the H1 region: written by finalize AFTER gemm2 consumed H1,
    // read by g3 (which writes d_out — so it can't live in d_out).
    float* ss2 = (float*)ws;

    hipMemsetAsync(sums1, 0, 2 * 2 * HID * sizeof(float), stream);

    prep_kernel<<<B_GRAPHS, 512, 0, stream>>>(x, W1, b1, gbias);
    cvt_kernel<<<(HID * HID / 8) / 256, 256, 0, stream>>>(W2, W2bf);

    gemm1_kernel<<<dim3(M_TOT / 128, 1), 512, 0, stream>>>(
        cond, W1, gbias, sums1, H1);

    gemm2_kernel<<<dim3(M_TOT / 128, 1), 512, 0, stream>>>(
        H1, W2bf, sums1, g1, be1, b2, sums2, H2);

    finalize_kernel<<<1, HID, 0, stream>>>(sums2, g2, be2, ss2);

    g3_kernel<<<M_TOT / 32, 256, 0, stream>>>(H2, ss2, W3, b3, outf);
}

// Round 8
// 291.883 us; speedup vs baseline: 2.4021x; 1.0203x over previous
//
#include <hip/hip_runtime.h>
#include <hip/hip_bf16.h>
#include <math.h>
#include <stdint.h>

#define B_GRAPHS 64
#define N_NODES  2048
#define E_DIM    16
#define M_TOT    (B_GRAPHS * N_NODES)   // 131072
#define K_COND   64
#define MLP_IN   192
#define HID      512
#define POOLD    128
#define BN_EPS   1e-5f

typedef __attribute__((ext_vector_type(8))) short bfrag8;
typedef __attribute__((ext_vector_type(4))) float facc4;

__device__ __forceinline__ unsigned short f2b(float f) {
    unsigned int x = __builtin_bit_cast(unsigned int, f);
    unsigned int r = x + 0x7fffu + ((x >> 16) & 1u);
    return (unsigned short)(r >> 16);
}
__device__ __forceinline__ float b2f(unsigned short u) {
    unsigned int x = ((unsigned int)u) << 16;
    return __builtin_bit_cast(float, x);
}

// Branch-free GELU: erf via Abramowitz-Stegun 7.1.26 (|err| <= 1.5e-7).
__device__ __forceinline__ float gelu_fast(float y) {
    float x  = y * 0.70710678118654752440f;
    float ax = fabsf(x);
    float t  = __builtin_amdgcn_rcpf(fmaf(0.3275911f, ax, 1.0f));
    float p  = fmaf(1.061405429f, t, -1.453152027f);
    p = fmaf(p, t, 1.421413741f);
    p = fmaf(p, t, -0.284496736f);
    p = fmaf(p, t, 0.254829592f);
    p = p * t;
    float e = __expf(-x * x);
    float erfax = fmaf(-p, e, 1.0f);
    float erfx  = copysignf(erfax, x);
    return 0.5f * y * (1.0f + erfx);
}

#define GLOAD_LDS16(g, l)                                                        \
    __builtin_amdgcn_global_load_lds(                                            \
        (const __attribute__((address_space(1))) unsigned int*)(const void*)(g), \
        (__attribute__((address_space(3))) unsigned int*)(void*)(l), 16, 0, 0)

// ---------------- prep: pooled (LDS) -> gbias[g][n] = pooled . W1[n,64:192] + b1[n] ----------------
__global__ __launch_bounds__(512) void prep_kernel(const float* __restrict__ x,
                                                   const float* __restrict__ W1,
                                                   const float* __restrict__ b1,
                                                   float* __restrict__ gbias) {
    __shared__ float pl[POOLD];
    int g = blockIdx.x, t = threadIdx.x;
    if (t < 128) {
        int h = t >> 2, w = t & 3;
        const float* base = x + (size_t)g * N_NODES * E_DIM + (size_t)h * 64 * E_DIM + w * 4;
        float s = 0.f;
        #pragma unroll 4
        for (int r = 0; r < 64; ++r) {
            float4 v = *reinterpret_cast<const float4*>(base + (size_t)r * E_DIM);
            s += v.x + v.y + v.z + v.w;
        }
        pl[h * 4 + w] = s * (1.0f / 256.0f);
    }
    __syncthreads();
    const float* wr_ = W1 + (size_t)t * MLP_IN + K_COND;
    float s = b1[t];
    #pragma unroll 4
    for (int k = 0; k < POOLD; ++k) s = fmaf(pl[k], wr_[k], s);
    gbias[g * HID + t] = s;
}

// ------------- contiguous fp32 -> bf16 (for W2) -------------
__global__ __launch_bounds__(256) void cvt_kernel(const float* __restrict__ s,
                                                  unsigned short* __restrict__ d) {
    size_t i = ((size_t)blockIdx.x * 256 + threadIdx.x) * 8;
    float4 v0 = *reinterpret_cast<const float4*>(s + i);
    float4 v1 = *reinterpret_cast<const float4*>(s + i + 4);
    unsigned short t[8] = {f2b(v0.x), f2b(v0.y), f2b(v0.z), f2b(v0.w),
                           f2b(v1.x), f2b(v1.y), f2b(v1.z), f2b(v1.w)};
    *reinterpret_cast<bfrag8*>(d + i) = *reinterpret_cast<bfrag8*>(t);
}

__device__ __forceinline__ bfrag8 load_f32x8_as_bf16(const float* p) {
    float4 v0 = *reinterpret_cast<const float4*>(p);
    float4 v1 = *reinterpret_cast<const float4*>(p + 4);
    unsigned short t[8] = {f2b(v0.x), f2b(v0.y), f2b(v0.z), f2b(v0.w),
                           f2b(v1.x), f2b(v1.y), f2b(v1.z), f2b(v1.w)};
    return *reinterpret_cast<bfrag8*>(t);
}

// ------------- GEMM1: H1 = cond[.,0:64] @ W1[.,0:64]^T + gbias[row>>11], fused stats -------------
// BM=128 x BN=512 full width (grid.y=1, cond read once), 8 waves (2x4), no LDS staging.
__global__ __launch_bounds__(512, 1) void gemm1_kernel(const float* __restrict__ A,
                                                       const float* __restrict__ W,
                                                       const float* __restrict__ gbias,
                                                       float* __restrict__ sums,
                                                       unsigned short* __restrict__ C) {
    __shared__ float sArr[HID], qArr[HID];
    const int t = threadIdx.x;
    const int r0 = blockIdx.x * 128;
    const int g = r0 >> 11;              // batch id (sorted repeat: row/2048)
    const int l = t & 63, w = t >> 6;
    const int wr = w >> 2, wc = w & 3;   // 2 x 4 waves
    const int ln = l & 15, kg = l >> 4;
    sArr[t] = 0.f; qArr[t] = 0.f;
    __syncthreads();

    facc4 acc[4][8];
    const facc4 z = {0.f, 0.f, 0.f, 0.f};
    #pragma unroll
    for (int a = 0; a < 4; ++a)
        #pragma unroll
        for (int b = 0; b < 8; ++b) acc[a][b] = z;

    #pragma unroll
    for (int ks = 0; ks < 2; ++ks) {
        bfrag8 af[4], bf[8];
        #pragma unroll
        for (int a = 0; a < 4; ++a)
            af[a] = load_f32x8_as_bf16(A + (size_t)(r0 + wr * 64 + a * 16 + ln) * K_COND + ks * 32 + kg * 8);
        #pragma unroll
        for (int b = 0; b < 8; ++b)
            bf[b] = load_f32x8_as_bf16(W + (size_t)(wc * 128 + b * 16 + ln) * MLP_IN + ks * 32 + kg * 8);
        #pragma unroll
        for (int a = 0; a < 4; ++a)
            #pragma unroll
            for (int b = 0; b < 8; ++b)
                acc[a][b] = __builtin_amdgcn_mfma_f32_16x16x32_bf16(af[a], bf[b], acc[a][b], 0, 0, 0);
    }

    const float* gb = gbias + (size_t)g * HID;
    float gbv[8];
    #pragma unroll
    for (int b = 0; b < 8; ++b) gbv[b] = gb[wc * 128 + b * 16 + ln];
    float cs[8], cq[8];
    #pragma unroll
    for (int b = 0; b < 8; ++b) { cs[b] = 0.f; cq[b] = 0.f; }
    #pragma unroll
    for (int a = 0; a < 4; ++a) {
        #pragma unroll
        for (int i = 0; i < 4; ++i) {
            size_t rbase = (size_t)(r0 + wr * 64 + a * 16 + kg * 4 + i) * HID + wc * 128 + ln;
            #pragma unroll
            for (int b = 0; b < 8; ++b) {
                float v = acc[a][b][i] + gbv[b];
                C[rbase + b * 16] = f2b(v);
                cs[b] += v; cq[b] = fmaf(v, v, cq[b]);
            }
        }
    }
    #pragma unroll
    for (int b = 0; b < 8; ++b) {
        cs[b] += __shfl_xor(cs[b], 16, 64); cq[b] += __shfl_xor(cq[b], 16, 64);
        cs[b] += __shfl_xor(cs[b], 32, 64); cq[b] += __shfl_xor(cq[b], 32, 64);
    }
    if (kg == 0) {
        #pragma unroll
        for (int b = 0; b < 8; ++b) {
            int cl = wc * 128 + b * 16 + ln;
            atomicAdd(&sArr[cl], cs[b]); atomicAdd(&qArr[cl], cq[b]);
        }
    }
    __syncthreads();
    atomicAdd(&sums[t], sArr[t]);
    atomicAdd(&sums[HID + t], qArr[t]);
}

// ------------- GEMM2: H2 = gelu(bn1(H1)) @ W2^T + b2, fused act1 + stats2 -------------
// BM=128 x BN=512, 8 waves. Triple-buffered B (2-deep prefetch) + double-buffered A:
// ONE barrier per K-step, counted vmcnt(4), no sched pinning (compiler schedules
// ds_read/MFMA with counted lgkm), setprio around MFMA cluster.
__global__ __launch_bounds__(512, 1) void gemm2_kernel(const unsigned short* __restrict__ A,
                                                       const unsigned short* __restrict__ Bm,
                                                       const float* __restrict__ sums1,
                                                       const float* __restrict__ g1,
                                                       const float* __restrict__ be1,
                                                       const float* __restrict__ bias,
                                                       float* __restrict__ sums,
                                                       unsigned short* __restrict__ C) {
    __shared__ unsigned short As[2][128 * 32];   // 16KB
    __shared__ unsigned short Bs[3][512 * 32];   // 96KB
    __shared__ float lss[2 * HID];               // 4KB
    __shared__ float sArr[HID], qArr[HID];       // 4KB   (total 120KB -> 1 block/CU)
    const int t = threadIdx.x;
    const int r0 = blockIdx.x * 128;
    const int l = t & 63, w = t >> 6;            // 8 waves
    const int wr = w >> 2, wc = w & 3;           // 2 x 4
    const int ln = l & 15, kg = l >> 4;
    const int arow = t >> 2, aslot = t & 3;
    const int awslot = aslot ^ ((arow >> 1) & 3);
    const int rr = l >> 2, sp = l & 3;
    const int bss = sp ^ ((rr >> 1) & 3);        // B pre-swizzled source slot

    // BN1 scale/shift from raw sums (folds finalize1)
    {
        float mean = sums1[t] * (1.0f / M_TOT);
        float var  = sums1[HID + t] * (1.0f / M_TOT) - mean * mean;
        float sc   = g1[t] * rsqrtf(var + BN_EPS);
        lss[t] = sc;
        lss[HID + t] = be1[t] - mean * sc;
    }
    sArr[t] = 0.f; qArr[t] = 0.f;

    facc4 acc[4][8];
    const facc4 z = {0.f, 0.f, 0.f, 0.f};
    #pragma unroll
    for (int a = 0; a < 4; ++a)
        #pragma unroll
        for (int b = 0; b < 8; ++b) acc[a][b] = z;

    const unsigned short* aptr = A + (size_t)(r0 + arow) * HID + aslot * 8;

    auto actwrite = [&](bfrag8 va, int kk, unsigned short* asb) {
        unsigned short tmp[8];
        #pragma unroll
        for (int j = 0; j < 8; ++j) {
            int col = kk + aslot * 8 + j;
            float xv = b2f((unsigned short)va[j]);
            tmp[j] = f2b(gelu_fast(fmaf(xv, lss[col], lss[HID + col])));
        }
        *reinterpret_cast<bfrag8*>(&asb[arow * 32 + awslot * 8]) = *reinterpret_cast<bfrag8*>(tmp);
    };
    auto stageB = [&](int kk, unsigned short* bsb) {
        #pragma unroll
        for (int c = 0; c < 4; ++c) {
            int chunk = w * 4 + c;                // 32 chunks x 16 rows
            const unsigned short* gb = Bm + (size_t)(chunk * 16 + rr) * HID + kk + bss * 8;
            GLOAD_LDS16(gb, &bsb[chunk * 512]);
        }
    };

    __syncthreads();  // lss/sArr ready

    // prologue — vmem queue: [AL0, B0x4, AL1, B1x4]
    bfrag8 va_p, va_q;
    va_p = *reinterpret_cast<const bfrag8*>(aptr);          // AL0
    stageB(0, Bs[0]);                                       // B0
    va_q = *reinterpret_cast<const bfrag8*>(aptr + 32);     // AL1
    stageB(32, Bs[1]);                                      // B1
    asm volatile("s_waitcnt vmcnt(9)" ::: "memory");        // retire AL0
    actwrite(va_p, 0, As[0]);
    va_p = va_q;
    asm volatile("s_waitcnt lgkmcnt(0)" ::: "memory");      // As[0] write drained

    unsigned short* bs_r  = Bs[0];
    unsigned short* bs_n1 = Bs[1];
    unsigned short* bs_n2 = Bs[2];
    unsigned short* as_r  = As[0];
    unsigned short* as_w  = As[1];

    for (int tt = 0; tt < 16; ++tt) {
        // retire B(tt) (+AL(tt+1)); keep B(tt+1)x4 in flight
        if (tt < 15) asm volatile("s_waitcnt vmcnt(4)" ::: "memory");
        else         asm volatile("s_waitcnt vmcnt(0)" ::: "memory");
        __builtin_amdgcn_s_barrier();   // everyone's DMA retired + prev ds ops drained
        // issue next-next tile: B(tt+2) -> bs_n2 (nobody reads it this step), AL(tt+2)
        if (tt < 14) {
            va_q = *reinterpret_cast<const bfrag8*>(aptr + (tt + 2) * 32);
            stageB((tt + 2) * 32, bs_n2);
        }
        // current fragments (normal loads: compiler emits counted lgkm before MFMA)
        bfrag8 af[4], bf[8];
        #pragma unroll
        for (int a = 0; a < 4; ++a) {
            int RA = wr * 64 + a * 16 + ln;
            af[a] = *reinterpret_cast<const bfrag8*>(&as_r[RA * 32 + (kg ^ ((RA >> 1) & 3)) * 8]);
        }
        #pragma unroll
        for (int b = 0; b < 8; ++b) {
            int RB = wc * 128 + b * 16 + ln;
            bf[b] = *reinterpret_cast<const bfrag8*>(&bs_r[RB * 32 + (kg ^ ((RB >> 1) & 3)) * 8]);
        }
        // act + ds_write A(tt+1) into the buffer nobody reads this step
        if (tt < 15) actwrite(va_p, (tt + 1) * 32, as_w);
        __builtin_amdgcn_s_setprio(1);
        #pragma unroll
        for (int a = 0; a < 4; ++a)
            #pragma unroll
            for (int b = 0; b < 8; ++b)
                acc[a][b] = __builtin_amdgcn_mfma_f32_16x16x32_bf16(af[a], bf[b], acc[a][b], 0, 0, 0);
        __builtin_amdgcn_s_setprio(0);
        asm volatile("s_waitcnt lgkmcnt(0)" ::: "memory");  // my reads+writes done before next barrier
        va_p = va_q;
        unsigned short* tmpb = bs_r; bs_r = bs_n1; bs_n1 = bs_n2; bs_n2 = tmpb;
        unsigned short* tmpa = as_r; as_r = as_w; as_w = tmpa;
    }

    float bb[8];
    #pragma unroll
    for (int b = 0; b < 8; ++b) bb[b] = bias[wc * 128 + b * 16 + ln];
    float cs[8], cq[8];
    #pragma unroll
    for (int b = 0; b < 8; ++b) { cs[b] = 0.f; cq[b] = 0.f; }
    #pragma unroll
    for (int a = 0; a < 4; ++a) {
        #pragma unroll
        for (int i = 0; i < 4; ++i) {
            size_t rbase = (size_t)(r0 + wr * 64 + a * 16 + kg * 4 + i) * HID + wc * 128 + ln;
            #pragma unroll
            for (int b = 0; b < 8; ++b) {
                float v = acc[a][b][i] + bb[b];
                C[rbase + b * 16] = f2b(v);
                cs[b] += v; cq[b] = fmaf(v, v, cq[b]);
            }
        }
    }
    #pragma unroll
    for (int b = 0; b < 8; ++b) {
        cs[b] += __shfl_xor(cs[b], 16, 64); cq[b] += __shfl_xor(cq[b], 16, 64);
        cs[b] += __shfl_xor(cs[b], 32, 64); cq[b] += __shfl_xor(cq[b], 32, 64);
    }
    if (kg == 0) {
        #pragma unroll
        for (int b = 0; b < 8; ++b) {
            int cl = wc * 128 + b * 16 + ln;
            atomicAdd(&sArr[cl], cs[b]); atomicAdd(&qArr[cl], cq[b]);
        }
    }
    __syncthreads();
    atomicAdd(&sums[t], sArr[t]);
    atomicAdd(&sums[HID + t], qArr[t]);
}

// ------------- finalize: ss[0:512]=scale, ss[512:1024]=shift -------------
__global__ void finalize_kernel(const float* __restrict__ sums, const float* __restrict__ g,
                                const float* __restrict__ be, float* __restrict__ ss) {
    int n = threadIdx.x;  // 512
    float mean = sums[n] * (1.0f / M_TOT);
    float var = sums[HID + n] * (1.0f / M_TOT) - mean * mean;
    float sc = g[n] * rsqrtf(var + BN_EPS);
    ss[n] = sc;
    ss[HID + n] = be[n] - mean * sc;
}

// ------------- G3: out[m][0:3] = gelu(bn2(H2[m])) . W3^T + b3  (8 lanes per row) -------------
__global__ __launch_bounds__(256) void g3_kernel(const unsigned short* __restrict__ H2,
                                                 const float* __restrict__ ss2,
                                                 const float* __restrict__ W3,
                                                 const float* __restrict__ b3,
                                                 float* __restrict__ out) {
    __shared__ float lss[2 * HID];
    __shared__ float lw3[3 * HID];
    int t = threadIdx.x;
    for (int i = t; i < 2 * HID; i += 256) lss[i] = ss2[i];
    for (int i = t; i < 3 * HID; i += 256) lw3[i] = W3[i];
    __syncthreads();
    int l = t & 63, w = t >> 6;
    int rsub = l >> 3, lk = l & 7;
    int row = blockIdx.x * 32 + w * 8 + rsub;
    const unsigned short* p = H2 + (size_t)row * HID;
    float o0 = 0.f, o1 = 0.f, o2 = 0.f;
    #pragma unroll
    for (int it = 0; it < 8; ++it) {
        int k = it * 64 + lk * 8;
        bfrag8 v = *reinterpret_cast<const bfrag8*>(p + k);
        #pragma unroll
        for (int j = 0; j < 8; ++j) {
            float x = b2f((unsigned short)v[j]);
            float y = fmaf(x, lss[k + j], lss[HID + k + j]);
            y = gelu_fast(y);
            o0 = fmaf(y, lw3[k + j], o0);
            o1 = fmaf(y, lw3[HID + k + j], o1);
            o2 = fmaf(y, lw3[2 * HID + k + j], o2);
        }
    }
    #pragma unroll
    for (int m = 1; m < 8; m <<= 1) {
        o0 += __shfl_xor(o0, m, 64);
        o1 += __shfl_xor(o1, m, 64);
        o2 += __shfl_xor(o2, m, 64);
    }
    if (lk == 0) {
        out[(size_t)row * 3 + 0] = o0 + b3[0];
        out[(size_t)row * 3 + 1] = o1 + b3[1];
        out[(size_t)row * 3 + 2] = o2 + b3[2];
    }
}

extern "C" void kernel_launch(void* const* d_in, const int* in_sizes, int n_in,
                              void* d_out, int out_size, void* d_ws, size_t ws_size,
                              hipStream_t stream) {
    const float* x     = (const float*)d_in[0];
    const float* cond  = (const float*)d_in[2];
    const float* W1    = (const float*)d_in[3];
    const float* b1    = (const float*)d_in[4];
    const float* g1    = (const float*)d_in[5];
    const float* be1   = (const float*)d_in[6];
    const float* W2    = (const float*)d_in[7];
    const float* b2    = (const float*)d_in[8];
    const float* g2    = (const float*)d_in[9];
    const float* be2   = (const float*)d_in[10];
    const float* W3    = (const float*)d_in[11];
    const float* b3    = (const float*)d_in[12];

    const size_t H_BYTES = (size_t)M_TOT * HID * 2;  // 134,217,728
    if (ws_size < 2 * H_BYTES) return;               // clean fail instead of OOB crash
    char* ws = (char*)d_ws;
    unsigned short* H1 = (unsigned short*)ws;
    unsigned short* H2 = (unsigned short*)(ws + H_BYTES);

    // Small scratch lives in d_out (1.57MB) until g3 overwrites it.
    float* outf   = (float*)d_out;
    float* gbias  = outf;                        // 32768 floats
    float* sums1  = gbias + B_GRAPHS * HID;      // 1024 (sum | sumsq)
    float* sums2  = sums1 + 2 * HID;             // 1024
    unsigned short* W2bf = (unsigned short*)(sums2 + 2 * HID);  // 262144 shorts (512KB)
    // ss2 lives in the H1 region: written by finalize AFTER gemm2 consumed H1,
    // read by g3 (which writes d_out — so it can't live in d_out).
    float* ss2 = (float*)ws;

    hipMemsetAsync(sums1, 0, 2 * 2 * HID * sizeof(float), stream);

    prep_kernel<<<B_GRAPHS, 512, 0, stream>>>(x, W1, b1, gbias);
    cvt_kernel<<<(HID * HID / 8) / 256, 256, 0, stream>>>(W2, W2bf);

    gemm1_kernel<<<dim3(M_TOT / 128, 1), 512, 0, stream>>>(
        cond, W1, gbias, sums1, H1);

    gemm2_kernel<<<dim3(M_TOT / 128, 1), 512, 0, stream>>>(
        H1, W2bf, sums1, g1, be1, b2, sums2, H2);

    finalize_kernel<<<1, HID, 0, stream>>>(sums2, g2, be2, ss2);

    g3_kernel<<<M_TOT / 32, 256, 0, stream>>>(H2, ss2, W3, b3, outf);
}